// Round 5
// baseline (685.697 us; speedup 1.0000x reference)
//
#include <hip/hip_runtime.h>
#include <stdint.h>

#define NN 100000
#define NE 1000000
#define NTILES (NE / 64)
#define NB_SCAN 391  // ceil(NN/256)

typedef __attribute__((ext_vector_type(8))) short bf16x8;
typedef __attribute__((ext_vector_type(4))) float f32x4;

// ws layout (bytes)
static const size_t OFF_W1K   = 0;                    // 128*32 bf16 (8 KB)
static const size_t OFF_W1BP  = 8192;                 // 128*128 bf16 (32 KB)
static const size_t OFF_MTB   = 40960;                // 128*128 bf16 (32 KB): mtb[i][l]
static const size_t OFF_RP    = 73728;                // (NN+1) int rowptr
static const size_t OFF_CUR   = 524288;               // NN int cursor
static const size_t OFF_PART  = 1048576;              // NB_SCAN*256 int
static const size_t OFF_BSUM  = 1572864;              // NB_SCAN int
static const size_t OFF_BSUMX = 1576960;              // NB_SCAN int
static const size_t OFF_CNT   = 1581056;              // NN int histogram
static const size_t OFF_PERM  = 2097152;              // NE int
static const size_t OFF_EVALS = 8388608;              // NE f32
static const size_t OFF_SNODE = 1u << 24;             // NN*128 bf16 (25.6 MB)

__device__ inline unsigned short f2bf(float f) {
    const unsigned int u = __float_as_uint(f);
    return (unsigned short)((u + 0x7fffu + ((u >> 16) & 1u)) >> 16);  // RNE
}

// ---------------------------------------------------------------------------
// prep: w1k = bf16(Wk) K-padded to 32; w1bp = W1b slot-permuted bf16
// (phase-1 MFMA output order == phase-2 B-frag order); mtb[i][l] = bf16(M[i][l])
// where M = W1a@Wq (A-operand of the node-score MFMA).
// ---------------------------------------------------------------------------
__global__ __launch_bounds__(128) void prep_kernel(
    const float* __restrict__ W1, const float* __restrict__ Wq,
    const float* __restrict__ Wk,
    unsigned short* __restrict__ w1k, unsigned short* __restrict__ w1bp,
    unsigned short* __restrict__ mtb)
{
    const int l = blockIdx.x;   // 0..127
    const int i = threadIdx.x;  // 0..127
    float acc = 0.f;
#pragma unroll 8
    for (int j = 0; j < 128; ++j)
        acc = fmaf(W1[i * 256 + j], Wq[j * 128 + l], acc);
    mtb[i * 128 + l] = f2bf(acc);  // M[i][l], row-major bf16
    if (i < 32)
        w1k[l * 32 + i] = (i < 10) ? f2bf(Wk[l * 10 + i]) : (unsigned short)0;
    const int m = l;
    const int j = (m & ~31) + 16 * ((m >> 2) & 1) + 4 * ((m >> 3) & 3) + (m & 3);
    w1bp[i * 128 + m] = f2bf(W1[i * 256 + 128 + j]);
}

// ---------------------------------------------------------------------------
// node scores via MFMA: s_node[n][i] = bf16( x[n]@M^T + b1 )
// Wave handles 16 nodes (cols). A = M rows from LDS (same frag addressing as
// edge phase-2); B = x packed bf16 per lane; D-store mirrors the edge-kernel
// sn-read pattern: s_node[n*128 + g*16 + h*4 + r].
// ---------------------------------------------------------------------------
__global__ __launch_bounds__(256, 4) void node_score_kernel(
    const float* __restrict__ x, const unsigned short* __restrict__ mtb_g,
    const float* __restrict__ b1, unsigned short* __restrict__ s_node)
{
    __shared__ __align__(16) unsigned short mt_s[128 * 136];
    const int t = threadIdx.x;
    for (int idx = t; idx < 2048; idx += 256) {
        const uint4 v = ((const uint4*)mtb_g)[idx];
        const int row = idx >> 4, q = idx & 15;
        *(uint4*)&mt_s[row * 136 + q * 8] = v;
    }
    __syncthreads();

    const int lane = t & 63;
    const int wave = t >> 6;
    const int h    = lane >> 4;
    const int e15  = lane & 15;
    const int node = blockIdx.x * 64 + wave * 16 + e15;
    const int nc   = min(node, NN - 1);
    const int lds_base = e15 * 136 + h * 8;

    const f32x4 z4 = {0.f, 0.f, 0.f, 0.f};
    f32x4 acc[8];
#pragma unroll
    for (int g = 0; g < 8; ++g) acc[g] = z4;

#pragma unroll
    for (int s = 0; s < 4; ++s) {
        const float4 xa = *(const float4*)&x[(size_t)nc * 128 + s * 32 + h * 8];
        const float4 xb = *(const float4*)&x[(size_t)nc * 128 + s * 32 + h * 8 + 4];
        bf16x8 bx;
        bx[0] = (short)f2bf(xa.x); bx[1] = (short)f2bf(xa.y);
        bx[2] = (short)f2bf(xa.z); bx[3] = (short)f2bf(xa.w);
        bx[4] = (short)f2bf(xb.x); bx[5] = (short)f2bf(xb.y);
        bx[6] = (short)f2bf(xb.z); bx[7] = (short)f2bf(xb.w);
#pragma unroll
        for (int g = 0; g < 8; ++g) {
            const bf16x8 a = *(const bf16x8*)&mt_s[lds_base + g * (16 * 136) + s * 32];
            acc[g] = __builtin_amdgcn_mfma_f32_16x16x32_bf16(a, bx, acc[g], 0, 0, 0);
        }
    }

    if (node < NN) {
#pragma unroll
        for (int g = 0; g < 8; ++g) {
            const float4 bb = *(const float4*)&b1[g * 16 + h * 4];
            ushort4 o4;
            o4.x = f2bf(acc[g][0] + bb.x);
            o4.y = f2bf(acc[g][1] + bb.y);
            o4.z = f2bf(acc[g][2] + bb.z);
            o4.w = f2bf(acc[g][3] + bb.w);
            *(ushort4*)&s_node[(size_t)node * 128 + g * 16 + h * 4] = o4;
        }
    }
}

// ---------------------------------------------------------------------------
// CSR build: histogram -> block scan (3 kernels) -> fill perm
// ---------------------------------------------------------------------------
__global__ __launch_bounds__(256) void hist_kernel(
    const int* __restrict__ tgt, int* __restrict__ cnt)
{
    const int e = blockIdx.x * 256 + threadIdx.x;
    if (e < NE) atomicAdd(&cnt[tgt[e]], 1);
}

__global__ __launch_bounds__(256) void scan1_kernel(
    const int* __restrict__ cnt, int* __restrict__ part, int* __restrict__ bsum)
{
    __shared__ int s[256];
    const int t = threadIdx.x;
    const int idx = blockIdx.x * 256 + t;
    const int v = (idx < NN) ? cnt[idx] : 0;
    s[t] = v;
    __syncthreads();
    for (int off = 1; off < 256; off <<= 1) {
        const int u = (t >= off) ? s[t - off] : 0;
        __syncthreads();
        s[t] += u;
        __syncthreads();
    }
    part[idx] = s[t] - v;  // exclusive
    if (t == 255) bsum[blockIdx.x] = s[255];
}

__global__ __launch_bounds__(512) void scan2_kernel(
    const int* __restrict__ bsum, int* __restrict__ bsumx)
{
    __shared__ int s[512];
    const int t = threadIdx.x;
    const int v = (t < NB_SCAN) ? bsum[t] : 0;
    s[t] = v;
    __syncthreads();
    for (int off = 1; off < 512; off <<= 1) {
        const int u = (t >= off) ? s[t - off] : 0;
        __syncthreads();
        s[t] += u;
        __syncthreads();
    }
    if (t < NB_SCAN) bsumx[t] = s[t] - v;  // exclusive
}

__global__ __launch_bounds__(256) void scan3_kernel(
    const int* __restrict__ part, const int* __restrict__ bsumx,
    int* __restrict__ rowptr, int* __restrict__ cursor)
{
    const int idx = blockIdx.x * 256 + threadIdx.x;
    if (idx < NN) {
        const int rp = part[idx] + bsumx[idx >> 8];
        rowptr[idx] = rp;
        cursor[idx] = rp;
    }
    if (idx == 0) rowptr[NN] = NE;
}

__global__ __launch_bounds__(256) void fill_kernel(
    const int* __restrict__ tgt, int* __restrict__ cursor, int* __restrict__ perm)
{
    const int e = blockIdx.x * 256 + threadIdx.x;
    if (e < NE) {
        const int p = atomicAdd(&cursor[tgt[e]], 1);
        perm[p] = e;
    }
}

// ---------------------------------------------------------------------------
// edge scores via MFMA. launch_bounds(256,4) caps VGPR<=128 -> 16 waves/CU.
// tgt prefetched one tile ahead so the s_node gather issues at iter start.
// bf16 pack interleaved with phase-2 per K-chunk to cut live registers.
// ---------------------------------------------------------------------------
__global__ __launch_bounds__(256, 4) void edge_kernel(
    const float* __restrict__ edge_attr, const int* __restrict__ tgt,
    const unsigned short* __restrict__ w1k_g, const unsigned short* __restrict__ w1bp_g,
    const float* __restrict__ W2, const float* __restrict__ b2,
    const unsigned short* __restrict__ s_node,
    float* __restrict__ e_vals)
{
    __shared__ __align__(16) unsigned short w1b_s[128 * 136];

    const int t = threadIdx.x;
    for (int idx = t; idx < 2048; idx += 256) {
        const uint4 v = ((const uint4*)w1bp_g)[idx];
        const int row = idx >> 4, q = idx & 15;
        *(uint4*)&w1b_s[row * 136 + q * 8] = v;
    }

    const int lane = t & 63;
    const int wave = t >> 6;
    const int h    = lane >> 4;
    const int e15  = lane & 15;

    bf16x8 a1[8];
#pragma unroll
    for (int f = 0; f < 8; ++f)
        a1[f] = *(const bf16x8*)&w1k_g[(f * 16 + e15) * 32 + h * 8];
    const float b2v = b2[0];

    __syncthreads();

    const int lds_base = e15 * 136 + h * 8;
    const int estep    = gridDim.x * 64;

    int e  = blockIdx.x * 64 + wave * 16 + e15;
    int tg = (e < NE) ? tgt[e] : 0;

    for (int tile = blockIdx.x; tile < NTILES; tile += gridDim.x, e += estep) {
        // s_node gather first (tg known from prefetch) — hides under MFMA
        uint2 sn[8];
#pragma unroll
        for (int g = 0; g < 8; ++g)
            sn[g] = *(const uint2*)&s_node[(size_t)tg * 128 + g * 16 + h * 4];

        // prefetch next tile's target
        const int tg_next = (tile + (int)gridDim.x < NTILES) ? tgt[e + estep] : 0;

        // B1 frag: edge_attr channels c = h*8 + [0..7], zeros past c=9
        bf16x8 b1 = (bf16x8){0, 0, 0, 0, 0, 0, 0, 0};
        const float* pa = edge_attr + (size_t)e * 10;
        if (h == 0) {
            const float2 u0 = *(const float2*)(pa + 0);
            const float2 u1 = *(const float2*)(pa + 2);
            const float2 u2 = *(const float2*)(pa + 4);
            const float2 u3 = *(const float2*)(pa + 6);
            b1[0] = (short)f2bf(u0.x); b1[1] = (short)f2bf(u0.y);
            b1[2] = (short)f2bf(u1.x); b1[3] = (short)f2bf(u1.y);
            b1[4] = (short)f2bf(u2.x); b1[5] = (short)f2bf(u2.y);
            b1[6] = (short)f2bf(u3.x); b1[7] = (short)f2bf(u3.y);
        } else if (h == 1) {
            const float2 u4 = *(const float2*)(pa + 8);
            b1[0] = (short)f2bf(u4.x); b1[1] = (short)f2bf(u4.y);
        }

        // phase 1: k[j][e], j = 16f + 4h + r
        const f32x4 z4 = {0.f, 0.f, 0.f, 0.f};
        f32x4 acc1[8];
#pragma unroll
        for (int f = 0; f < 8; ++f)
            acc1[f] = __builtin_amdgcn_mfma_f32_16x16x32_bf16(a1[f], b1, z4, 0, 0, 0);

        // phase 2 interleaved with pack: per K-chunk s, pack pbf then 8 MFMA
        f32x4 acc2[8];
#pragma unroll
        for (int g = 0; g < 8; ++g) acc2[g] = z4;
#pragma unroll
        for (int s = 0; s < 4; ++s) {
            bf16x8 pb;
#pragma unroll
            for (int e8 = 0; e8 < 8; ++e8) {
                float v = acc1[2 * s + (e8 >> 2)][e8 & 3];
                v = (v >= 0.f) ? v : 0.01f * v;
                pb[e8] = (short)f2bf(v);
            }
#pragma unroll
            for (int g = 0; g < 8; ++g) {
                const bf16x8 a2 = *(const bf16x8*)&w1b_s[lds_base + g * (16 * 136) + s * 32];
                acc2[g] = __builtin_amdgcn_mfma_f32_16x16x32_bf16(a2, pb, acc2[g], 0, 0, 0);
            }
        }

        // epilogue: p = sum_i relu(t + s_node) * W2, reduce over h-groups
        float p = 0.f;
#pragma unroll
        for (int g = 0; g < 8; ++g) {
            const float4 w2v = *(const float4*)&W2[g * 16 + h * 4];
            const uint2 sv = sn[g];
            const float s0 = __uint_as_float(sv.x << 16);
            const float s1 = __uint_as_float(sv.x & 0xffff0000u);
            const float s2 = __uint_as_float(sv.y << 16);
            const float s3 = __uint_as_float(sv.y & 0xffff0000u);
            p = fmaf(fmaxf(acc2[g][0] + s0, 0.f), w2v.x, p);
            p = fmaf(fmaxf(acc2[g][1] + s1, 0.f), w2v.y, p);
            p = fmaf(fmaxf(acc2[g][2] + s2, 0.f), w2v.z, p);
            p = fmaf(fmaxf(acc2[g][3] + s3, 0.f), w2v.w, p);
        }
        p += __shfl_xor(p, 16);
        p += __shfl_xor(p, 32);
        if (lane < 16)
            e_vals[e] = expf(p + b2v);  // |score| small; no max-shift

        tg = tg_next;
    }
}

// ---------------------------------------------------------------------------
// gather: one wave per node, lane owns dims (2*lane, 2*lane+1).
// ---------------------------------------------------------------------------
__global__ __launch_bounds__(256) void gather_kernel(
    const int* __restrict__ rowptr, const int* __restrict__ perm,
    const float* __restrict__ e_vals, const float* __restrict__ edge_attr,
    const float* __restrict__ Wv, const float* __restrict__ bv,
    float* __restrict__ out, float* __restrict__ attn_out)
{
    const int t    = threadIdx.x;
    const int lane = t & 63;
    const int wave = t >> 6;
    const int node = blockIdx.x * 4 + wave;
    const int d0   = lane * 2;

    float wv0[10], wv1[10];
#pragma unroll
    for (int c = 0; c < 10; ++c) {
        wv0[c] = Wv[d0 * 10 + c];
        wv1[c] = Wv[d0 * 10 + 10 + c];
    }
    const float bv0 = bv[d0], bv1 = bv[d0 + 1];

    const int start = rowptr[node];
    const int end   = rowptr[node + 1];

    // phase A: denominator
    float part = 0.f;
    for (int c = start + lane; c < end; c += 64) part += e_vals[perm[c]];
    part += __shfl_xor(part, 1);
    part += __shfl_xor(part, 2);
    part += __shfl_xor(part, 4);
    part += __shfl_xor(part, 8);
    part += __shfl_xor(part, 16);
    part += __shfl_xor(part, 32);
    const float inv = 1.f / (part + 1e-16f);

    float acc0 = 0.f, acc1 = 0.f;
    for (int c0 = start; c0 < end; c0 += 64) {
        const int m = min(64, end - c0);
        int ee = 0; float evl = 0.f;
        if (lane < m) {
            ee  = perm[c0 + lane];
            evl = e_vals[ee];
            attn_out[ee] = evl * inv;
        }
#pragma unroll 2
        for (int d = 0; d < m; ++d) {
            const int   eed = __shfl(ee, d);
            const float ad  = __shfl(evl, d) * inv;
            const float* pa = edge_attr + (size_t)eed * 10;
            const float2 u0 = *(const float2*)(pa + 0);
            const float2 u1 = *(const float2*)(pa + 2);
            const float2 u2 = *(const float2*)(pa + 4);
            const float2 u3 = *(const float2*)(pa + 6);
            const float2 u4 = *(const float2*)(pa + 8);
            float a0 = bv0, a1 = bv1;
            a0 = fmaf(u0.x, wv0[0], a0); a1 = fmaf(u0.x, wv1[0], a1);
            a0 = fmaf(u0.y, wv0[1], a0); a1 = fmaf(u0.y, wv1[1], a1);
            a0 = fmaf(u1.x, wv0[2], a0); a1 = fmaf(u1.x, wv1[2], a1);
            a0 = fmaf(u1.y, wv0[3], a0); a1 = fmaf(u1.y, wv1[3], a1);
            a0 = fmaf(u2.x, wv0[4], a0); a1 = fmaf(u2.x, wv1[4], a1);
            a0 = fmaf(u2.y, wv0[5], a0); a1 = fmaf(u2.y, wv1[5], a1);
            a0 = fmaf(u3.x, wv0[6], a0); a1 = fmaf(u3.x, wv1[6], a1);
            a0 = fmaf(u3.y, wv0[7], a0); a1 = fmaf(u3.y, wv1[7], a1);
            a0 = fmaf(u4.x, wv0[8], a0); a1 = fmaf(u4.x, wv1[8], a1);
            a0 = fmaf(u4.y, wv0[9], a0); a1 = fmaf(u4.y, wv1[9], a1);
            const float v0 = (a0 >= 0.f) ? a0 : 0.01f * a0;
            const float v1 = (a1 >= 0.f) ? a1 : 0.01f * a1;
            acc0 = fmaf(ad, v0, acc0);
            acc1 = fmaf(ad, v1, acc1);
        }
    }
    *(float2*)&out[(size_t)node * 128 + d0] = make_float2(acc0, acc1);
}

extern "C" void kernel_launch(void* const* d_in, const int* in_sizes, int n_in,
                              void* d_out, int out_size, void* d_ws, size_t ws_size,
                              hipStream_t stream)
{
    const float* x         = (const float*)d_in[0];
    const int*   eidx      = (const int*)d_in[1];
    const float* edge_attr = (const float*)d_in[2];
    const float* Wq        = (const float*)d_in[3];
    const float* Wk        = (const float*)d_in[4];
    const float* Wv        = (const float*)d_in[5];
    const float* bv        = (const float*)d_in[6];
    const float* W1        = (const float*)d_in[7];
    const float* b1        = (const float*)d_in[8];
    const float* W2        = (const float*)d_in[9];
    const float* b2        = (const float*)d_in[10];
    const int*   tgt       = eidx + NE;  // edge_index[1]

    char* ws = (char*)d_ws;
    unsigned short* w1k    = (unsigned short*)(ws + OFF_W1K);
    unsigned short* w1bp   = (unsigned short*)(ws + OFF_W1BP);
    unsigned short* mtb    = (unsigned short*)(ws + OFF_MTB);
    int*            rowptr = (int*)(ws + OFF_RP);
    int*            cursor = (int*)(ws + OFF_CUR);
    int*            part   = (int*)(ws + OFF_PART);
    int*            bsum   = (int*)(ws + OFF_BSUM);
    int*            bsumx  = (int*)(ws + OFF_BSUMX);
    int*            cnt    = (int*)(ws + OFF_CNT);
    int*            perm   = (int*)(ws + OFF_PERM);
    float*          e_vals = (float*)(ws + OFF_EVALS);
    unsigned short* s_node = (unsigned short*)(ws + OFF_SNODE);

    float* out      = (float*)d_out;
    float* attn_out = out + (size_t)NN * 128;

    hipMemsetAsync(cnt, 0, (size_t)NN * sizeof(int), stream);

    prep_kernel<<<128, 128, 0, stream>>>(W1, Wq, Wk, w1k, w1bp, mtb);
    node_score_kernel<<<(NN + 63) / 64, 256, 0, stream>>>(x, mtb, b1, s_node);
    hist_kernel<<<(NE + 255) / 256, 256, 0, stream>>>(tgt, cnt);
    scan1_kernel<<<NB_SCAN, 256, 0, stream>>>(cnt, part, bsum);
    scan2_kernel<<<1, 512, 0, stream>>>(bsum, bsumx);
    scan3_kernel<<<NB_SCAN, 256, 0, stream>>>(part, bsumx, rowptr, cursor);
    fill_kernel<<<(NE + 255) / 256, 256, 0, stream>>>(tgt, cursor, perm);
    edge_kernel<<<1024, 256, 0, stream>>>(edge_attr, tgt, w1k, w1bp, W2, b2,
                                          s_node, e_vals);
    gather_kernel<<<NN / 4, 256, 0, stream>>>(rowptr, perm, e_vals, edge_attr,
                                              Wv, bv, out, attn_out);
}

// Round 6
// 583.406 us; speedup vs baseline: 1.1753x; 1.1753x over previous
//
#include <hip/hip_runtime.h>
#include <stdint.h>

#define NN 100000
#define NE 1000000
#define NTILES (NE / 64)
#define NB_SCAN 391  // ceil(NN/256)

typedef __attribute__((ext_vector_type(8))) short bf16x8;
typedef __attribute__((ext_vector_type(4))) float f32x4;

// ws layout (bytes)
static const size_t OFF_W1K   = 0;                    // 128*32 bf16 (8 KB)
static const size_t OFF_W1BP  = 8192;                 // 128*128 bf16 (32 KB)
static const size_t OFF_MTB   = 40960;                // 128*128 bf16 (32 KB)
static const size_t OFF_RP    = 73728;                // (NN+1) int rowptr
static const size_t OFF_CUR   = 524288;               // NN int cursor
static const size_t OFF_PART  = 1048576;              // NB_SCAN*256 int
static const size_t OFF_BSUM  = 1572864;              // NB_SCAN int
static const size_t OFF_BSUMX = 1576960;              // NB_SCAN int
static const size_t OFF_CNT   = 1581056;              // NN int histogram
static const size_t OFF_PT    = 2097152;              // NE int2 {edge, tgt} sorted (8 MB)
static const size_t OFF_EVALS = 10485760;             // NE f32 (sorted order)
static const size_t OFF_SNODE = 1u << 24;             // NN*128 bf16 (25.6 MB)

__device__ inline unsigned short f2bf(float f) {
    const unsigned int u = __float_as_uint(f);
    return (unsigned short)((u + 0x7fffu + ((u >> 16) & 1u)) >> 16);  // RNE
}

// ---------------------------------------------------------------------------
// prep: w1k = bf16(Wk) K-padded to 32; w1bp = W1b slot-permuted bf16;
// mtb[i][l] = bf16((W1a@Wq)[i][l]).
// ---------------------------------------------------------------------------
__global__ __launch_bounds__(128) void prep_kernel(
    const float* __restrict__ W1, const float* __restrict__ Wq,
    const float* __restrict__ Wk,
    unsigned short* __restrict__ w1k, unsigned short* __restrict__ w1bp,
    unsigned short* __restrict__ mtb)
{
    const int l = blockIdx.x;   // 0..127
    const int i = threadIdx.x;  // 0..127
    float acc = 0.f;
#pragma unroll 8
    for (int j = 0; j < 128; ++j)
        acc = fmaf(W1[i * 256 + j], Wq[j * 128 + l], acc);
    mtb[i * 128 + l] = f2bf(acc);
    if (i < 32)
        w1k[l * 32 + i] = (i < 10) ? f2bf(Wk[l * 10 + i]) : (unsigned short)0;
    const int m = l;
    const int j = (m & ~31) + 16 * ((m >> 2) & 1) + 4 * ((m >> 3) & 3) + (m & 3);
    w1bp[i * 128 + m] = f2bf(W1[i * 256 + 128 + j]);
}

// ---------------------------------------------------------------------------
// node scores via MFMA: s_node[n][i] = bf16( x[n]@M^T + b1 )
// ---------------------------------------------------------------------------
__global__ __launch_bounds__(256) void node_score_kernel(
    const float* __restrict__ x, const unsigned short* __restrict__ mtb_g,
    const float* __restrict__ b1, unsigned short* __restrict__ s_node)
{
    __shared__ __align__(16) unsigned short mt_s[128 * 136];
    const int t = threadIdx.x;
    for (int idx = t; idx < 2048; idx += 256) {
        const uint4 v = ((const uint4*)mtb_g)[idx];
        const int row = idx >> 4, q = idx & 15;
        *(uint4*)&mt_s[row * 136 + q * 8] = v;
    }
    __syncthreads();

    const int lane = t & 63;
    const int wave = t >> 6;
    const int h    = lane >> 4;
    const int e15  = lane & 15;
    const int node = blockIdx.x * 64 + wave * 16 + e15;
    const int nc   = min(node, NN - 1);
    const int lds_base = e15 * 136 + h * 8;

    const f32x4 z4 = {0.f, 0.f, 0.f, 0.f};
    f32x4 acc[8];
#pragma unroll
    for (int g = 0; g < 8; ++g) acc[g] = z4;

#pragma unroll
    for (int s = 0; s < 4; ++s) {
        const float4 xa = *(const float4*)&x[(size_t)nc * 128 + s * 32 + h * 8];
        const float4 xb = *(const float4*)&x[(size_t)nc * 128 + s * 32 + h * 8 + 4];
        bf16x8 bx;
        bx[0] = (short)f2bf(xa.x); bx[1] = (short)f2bf(xa.y);
        bx[2] = (short)f2bf(xa.z); bx[3] = (short)f2bf(xa.w);
        bx[4] = (short)f2bf(xb.x); bx[5] = (short)f2bf(xb.y);
        bx[6] = (short)f2bf(xb.z); bx[7] = (short)f2bf(xb.w);
#pragma unroll
        for (int g = 0; g < 8; ++g) {
            const bf16x8 a = *(const bf16x8*)&mt_s[lds_base + g * (16 * 136) + s * 32];
            acc[g] = __builtin_amdgcn_mfma_f32_16x16x32_bf16(a, bx, acc[g], 0, 0, 0);
        }
    }

    if (node < NN) {
#pragma unroll
        for (int g = 0; g < 8; ++g) {
            const float4 bb = *(const float4*)&b1[g * 16 + h * 4];
            ushort4 o4;
            o4.x = f2bf(acc[g][0] + bb.x);
            o4.y = f2bf(acc[g][1] + bb.y);
            o4.z = f2bf(acc[g][2] + bb.z);
            o4.w = f2bf(acc[g][3] + bb.w);
            *(ushort4*)&s_node[(size_t)node * 128 + g * 16 + h * 4] = o4;
        }
    }
}

// ---------------------------------------------------------------------------
// CSR build: histogram -> block scan -> fill {edge,tgt} pairs in sorted order
// ---------------------------------------------------------------------------
__global__ __launch_bounds__(256) void hist_kernel(
    const int* __restrict__ tgt, int* __restrict__ cnt)
{
    const int e = blockIdx.x * 256 + threadIdx.x;
    if (e < NE) atomicAdd(&cnt[tgt[e]], 1);
}

__global__ __launch_bounds__(256) void scan1_kernel(
    const int* __restrict__ cnt, int* __restrict__ part, int* __restrict__ bsum)
{
    __shared__ int s[256];
    const int t = threadIdx.x;
    const int idx = blockIdx.x * 256 + t;
    const int v = (idx < NN) ? cnt[idx] : 0;
    s[t] = v;
    __syncthreads();
    for (int off = 1; off < 256; off <<= 1) {
        const int u = (t >= off) ? s[t - off] : 0;
        __syncthreads();
        s[t] += u;
        __syncthreads();
    }
    part[idx] = s[t] - v;  // exclusive
    if (t == 255) bsum[blockIdx.x] = s[255];
}

__global__ __launch_bounds__(512) void scan2_kernel(
    const int* __restrict__ bsum, int* __restrict__ bsumx)
{
    __shared__ int s[512];
    const int t = threadIdx.x;
    const int v = (t < NB_SCAN) ? bsum[t] : 0;
    s[t] = v;
    __syncthreads();
    for (int off = 1; off < 512; off <<= 1) {
        const int u = (t >= off) ? s[t - off] : 0;
        __syncthreads();
        s[t] += u;
        __syncthreads();
    }
    if (t < NB_SCAN) bsumx[t] = s[t] - v;  // exclusive
}

__global__ __launch_bounds__(256) void scan3_kernel(
    const int* __restrict__ part, const int* __restrict__ bsumx,
    int* __restrict__ rowptr, int* __restrict__ cursor)
{
    const int idx = blockIdx.x * 256 + threadIdx.x;
    if (idx < NN) {
        const int rp = part[idx] + bsumx[idx >> 8];
        rowptr[idx] = rp;
        cursor[idx] = rp;
    }
    if (idx == 0) rowptr[NN] = NE;
}

__global__ __launch_bounds__(256) void fill_kernel(
    const int* __restrict__ tgt, int* __restrict__ cursor, int2* __restrict__ pt)
{
    const int e = blockIdx.x * 256 + threadIdx.x;
    if (e < NE) {
        const int tg = tgt[e];
        const int p  = atomicAdd(&cursor[tg], 1);
        pt[p] = make_int2(e, tg);
    }
}

// ---------------------------------------------------------------------------
// edge scores via MFMA, processed in CSR-sorted order: consecutive sorted
// edges share tgt -> s_node row reads are L1/L2 hits instead of random HBM.
// Phase 2 restructured g-outer with per-g epilogue fold: acc2 is 2 f32x4
// instead of 8 -> fits 3-4 waves/SIMD without spills.
// e_vals written at SORTED index (coalesced; gather reads it coalesced too).
// ---------------------------------------------------------------------------
__global__ __launch_bounds__(256, 3) void edge_kernel(
    const float* __restrict__ edge_attr, const int2* __restrict__ pt,
    const unsigned short* __restrict__ w1k_g, const unsigned short* __restrict__ w1bp_g,
    const float* __restrict__ W2, const float* __restrict__ b2,
    const unsigned short* __restrict__ s_node,
    float* __restrict__ e_vals)
{
    __shared__ __align__(16) unsigned short w1b_s[128 * 136];

    const int t = threadIdx.x;
    for (int idx = t; idx < 2048; idx += 256) {
        const uint4 v = ((const uint4*)w1bp_g)[idx];
        const int row = idx >> 4, q = idx & 15;
        *(uint4*)&w1b_s[row * 136 + q * 8] = v;
    }

    const int lane = t & 63;
    const int wave = t >> 6;
    const int h    = lane >> 4;
    const int e15  = lane & 15;

    bf16x8 a1[8];
#pragma unroll
    for (int f = 0; f < 8; ++f)
        a1[f] = *(const bf16x8*)&w1k_g[(f * 16 + e15) * 32 + h * 8];
    const float b2v = b2[0];

    __syncthreads();

    const int lds_base = e15 * 136 + h * 8;
    const int cstep    = gridDim.x * 64;

    int c = blockIdx.x * 64 + wave * 16 + e15;  // sorted edge index
    int2 ptc = pt[min(c, NE - 1)];

    for (int tile = blockIdx.x; tile < NTILES; tile += gridDim.x, c += cstep) {
        const int ee = ptc.x;   // original edge id (for edge_attr)
        const int tg = ptc.y;   // target node

        // s_node row read — sorted order makes these mostly L1/L2 hits
        uint2 sn[8];
#pragma unroll
        for (int g = 0; g < 8; ++g)
            sn[g] = *(const uint2*)&s_node[(size_t)tg * 128 + g * 16 + h * 4];

        // prefetch next tile's {edge,tgt}
        if (tile + (int)gridDim.x < NTILES) ptc = pt[c + cstep];

        // B1 frag: edge_attr channels (gathered via ee)
        bf16x8 b1 = (bf16x8){0, 0, 0, 0, 0, 0, 0, 0};
        const float* pa = edge_attr + (size_t)ee * 10;
        if (h == 0) {
            const float2 u0 = *(const float2*)(pa + 0);
            const float2 u1 = *(const float2*)(pa + 2);
            const float2 u2 = *(const float2*)(pa + 4);
            const float2 u3 = *(const float2*)(pa + 6);
            b1[0] = (short)f2bf(u0.x); b1[1] = (short)f2bf(u0.y);
            b1[2] = (short)f2bf(u1.x); b1[3] = (short)f2bf(u1.y);
            b1[4] = (short)f2bf(u2.x); b1[5] = (short)f2bf(u2.y);
            b1[6] = (short)f2bf(u3.x); b1[7] = (short)f2bf(u3.y);
        } else if (h == 1) {
            const float2 u4 = *(const float2*)(pa + 8);
            b1[0] = (short)f2bf(u4.x); b1[1] = (short)f2bf(u4.y);
        }

        // phase 1: k[j][e], j = 16f + 4h + r
        const f32x4 z4 = {0.f, 0.f, 0.f, 0.f};
        f32x4 acc1[8];
#pragma unroll
        for (int f = 0; f < 8; ++f)
            acc1[f] = __builtin_amdgcn_mfma_f32_16x16x32_bf16(a1[f], b1, z4, 0, 0, 0);

        // pack all 4 B-frags (acc1 dies here)
        bf16x8 pb[4];
#pragma unroll
        for (int s = 0; s < 4; ++s) {
#pragma unroll
            for (int e8 = 0; e8 < 8; ++e8) {
                float v = acc1[2 * s + (e8 >> 2)][e8 & 3];
                v = (v >= 0.f) ? v : 0.01f * v;
                pb[s][e8] = (short)f2bf(v);
            }
        }

        // phase 2 g-outer (pairs), epilogue folded per pair: acc2 = 2 x f32x4
        float p = 0.f;
#pragma unroll
        for (int g2 = 0; g2 < 4; ++g2) {
            const int gA = 2 * g2, gB = 2 * g2 + 1;
            f32x4 accA = z4, accB = z4;
#pragma unroll
            for (int s = 0; s < 4; ++s) {
                const bf16x8 a2A = *(const bf16x8*)&w1b_s[lds_base + gA * (16 * 136) + s * 32];
                const bf16x8 a2B = *(const bf16x8*)&w1b_s[lds_base + gB * (16 * 136) + s * 32];
                accA = __builtin_amdgcn_mfma_f32_16x16x32_bf16(a2A, pb[s], accA, 0, 0, 0);
                accB = __builtin_amdgcn_mfma_f32_16x16x32_bf16(a2B, pb[s], accB, 0, 0, 0);
            }
            const float4 w2A = *(const float4*)&W2[gA * 16 + h * 4];
            const float4 w2B = *(const float4*)&W2[gB * 16 + h * 4];
            const uint2 svA = sn[gA], svB = sn[gB];
            p = fmaf(fmaxf(accA[0] + __uint_as_float(svA.x << 16), 0.f), w2A.x, p);
            p = fmaf(fmaxf(accA[1] + __uint_as_float(svA.x & 0xffff0000u), 0.f), w2A.y, p);
            p = fmaf(fmaxf(accA[2] + __uint_as_float(svA.y << 16), 0.f), w2A.z, p);
            p = fmaf(fmaxf(accA[3] + __uint_as_float(svA.y & 0xffff0000u), 0.f), w2A.w, p);
            p = fmaf(fmaxf(accB[0] + __uint_as_float(svB.x << 16), 0.f), w2B.x, p);
            p = fmaf(fmaxf(accB[1] + __uint_as_float(svB.x & 0xffff0000u), 0.f), w2B.y, p);
            p = fmaf(fmaxf(accB[2] + __uint_as_float(svB.y << 16), 0.f), w2B.z, p);
            p = fmaf(fmaxf(accB[3] + __uint_as_float(svB.y & 0xffff0000u), 0.f), w2B.w, p);
        }
        p += __shfl_xor(p, 16);
        p += __shfl_xor(p, 32);
        if (lane < 16)
            e_vals[c - e15 + lane] = expf(p + b2v);  // sorted index, coalesced

        // note: c - e15 + lane == tile*64 + wave*16 + lane for lane<16
    }
}

// ---------------------------------------------------------------------------
// gather: one wave per node. e_vals is in sorted order -> coalesced reads,
// no perm indirection for the denominator. pt gives edge id for edge_attr
// and attn_out scatter.
// ---------------------------------------------------------------------------
__global__ __launch_bounds__(256) void gather_kernel(
    const int* __restrict__ rowptr, const int2* __restrict__ pt,
    const float* __restrict__ e_vals, const float* __restrict__ edge_attr,
    const float* __restrict__ Wv, const float* __restrict__ bv,
    float* __restrict__ out, float* __restrict__ attn_out)
{
    const int t    = threadIdx.x;
    const int lane = t & 63;
    const int wave = t >> 6;
    const int node = blockIdx.x * 4 + wave;
    const int d0   = lane * 2;

    float wv0[10], wv1[10];
#pragma unroll
    for (int c = 0; c < 10; ++c) {
        wv0[c] = Wv[d0 * 10 + c];
        wv1[c] = Wv[d0 * 10 + 10 + c];
    }
    const float bv0 = bv[d0], bv1 = bv[d0 + 1];

    const int start = rowptr[node];
    const int end   = rowptr[node + 1];

    // phase A: denominator (coalesced e_vals)
    float part = 0.f;
    for (int c = start + lane; c < end; c += 64) part += e_vals[c];
    part += __shfl_xor(part, 1);
    part += __shfl_xor(part, 2);
    part += __shfl_xor(part, 4);
    part += __shfl_xor(part, 8);
    part += __shfl_xor(part, 16);
    part += __shfl_xor(part, 32);
    const float inv = 1.f / (part + 1e-16f);

    float acc0 = 0.f, acc1 = 0.f;
    for (int c0 = start; c0 < end; c0 += 64) {
        const int m = min(64, end - c0);
        int ee = 0; float evl = 0.f;
        if (lane < m) {
            ee  = pt[c0 + lane].x;
            evl = e_vals[c0 + lane];
            attn_out[ee] = evl * inv;
        }
#pragma unroll 2
        for (int d = 0; d < m; ++d) {
            const int   eed = __shfl(ee, d);
            const float ad  = __shfl(evl, d) * inv;
            const float* pa = edge_attr + (size_t)eed * 10;
            const float2 u0 = *(const float2*)(pa + 0);
            const float2 u1 = *(const float2*)(pa + 2);
            const float2 u2 = *(const float2*)(pa + 4);
            const float2 u3 = *(const float2*)(pa + 6);
            const float2 u4 = *(const float2*)(pa + 8);
            float a0 = bv0, a1 = bv1;
            a0 = fmaf(u0.x, wv0[0], a0); a1 = fmaf(u0.x, wv1[0], a1);
            a0 = fmaf(u0.y, wv0[1], a0); a1 = fmaf(u0.y, wv1[1], a1);
            a0 = fmaf(u1.x, wv0[2], a0); a1 = fmaf(u1.x, wv1[2], a1);
            a0 = fmaf(u1.y, wv0[3], a0); a1 = fmaf(u1.y, wv1[3], a1);
            a0 = fmaf(u2.x, wv0[4], a0); a1 = fmaf(u2.x, wv1[4], a1);
            a0 = fmaf(u2.y, wv0[5], a0); a1 = fmaf(u2.y, wv1[5], a1);
            a0 = fmaf(u3.x, wv0[6], a0); a1 = fmaf(u3.x, wv1[6], a1);
            a0 = fmaf(u3.y, wv0[7], a0); a1 = fmaf(u3.y, wv1[7], a1);
            a0 = fmaf(u4.x, wv0[8], a0); a1 = fmaf(u4.x, wv1[8], a1);
            a0 = fmaf(u4.y, wv0[9], a0); a1 = fmaf(u4.y, wv1[9], a1);
            const float v0 = (a0 >= 0.f) ? a0 : 0.01f * a0;
            const float v1 = (a1 >= 0.f) ? a1 : 0.01f * a1;
            acc0 = fmaf(ad, v0, acc0);
            acc1 = fmaf(ad, v1, acc1);
        }
    }
    *(float2*)&out[(size_t)node * 128 + d0] = make_float2(acc0, acc1);
}

extern "C" void kernel_launch(void* const* d_in, const int* in_sizes, int n_in,
                              void* d_out, int out_size, void* d_ws, size_t ws_size,
                              hipStream_t stream)
{
    const float* x         = (const float*)d_in[0];
    const int*   eidx      = (const int*)d_in[1];
    const float* edge_attr = (const float*)d_in[2];
    const float* Wq        = (const float*)d_in[3];
    const float* Wk        = (const float*)d_in[4];
    const float* Wv        = (const float*)d_in[5];
    const float* bv        = (const float*)d_in[6];
    const float* W1        = (const float*)d_in[7];
    const float* b1        = (const float*)d_in[8];
    const float* W2        = (const float*)d_in[9];
    const float* b2        = (const float*)d_in[10];
    const int*   tgt       = eidx + NE;  // edge_index[1]

    char* ws = (char*)d_ws;
    unsigned short* w1k    = (unsigned short*)(ws + OFF_W1K);
    unsigned short* w1bp   = (unsigned short*)(ws + OFF_W1BP);
    unsigned short* mtb    = (unsigned short*)(ws + OFF_MTB);
    int*            rowptr = (int*)(ws + OFF_RP);
    int*            cursor = (int*)(ws + OFF_CUR);
    int*            part   = (int*)(ws + OFF_PART);
    int*            bsum   = (int*)(ws + OFF_BSUM);
    int*            bsumx  = (int*)(ws + OFF_BSUMX);
    int*            cnt    = (int*)(ws + OFF_CNT);
    int2*           pt     = (int2*)(ws + OFF_PT);
    float*          e_vals = (float*)(ws + OFF_EVALS);
    unsigned short* s_node = (unsigned short*)(ws + OFF_SNODE);

    float* out      = (float*)d_out;
    float* attn_out = out + (size_t)NN * 128;

    hipMemsetAsync(cnt, 0, (size_t)NN * sizeof(int), stream);

    prep_kernel<<<128, 128, 0, stream>>>(W1, Wq, Wk, w1k, w1bp, mtb);
    node_score_kernel<<<(NN + 63) / 64, 256, 0, stream>>>(x, mtb, b1, s_node);
    hist_kernel<<<(NE + 255) / 256, 256, 0, stream>>>(tgt, cnt);
    scan1_kernel<<<NB_SCAN, 256, 0, stream>>>(cnt, part, bsum);
    scan2_kernel<<<1, 512, 0, stream>>>(bsum, bsumx);
    scan3_kernel<<<NB_SCAN, 256, 0, stream>>>(part, bsumx, rowptr, cursor);
    fill_kernel<<<(NE + 255) / 256, 256, 0, stream>>>(tgt, cursor, pt);
    edge_kernel<<<1024, 256, 0, stream>>>(edge_attr, pt, w1k, w1bp, W2, b2,
                                          s_node, e_vals);
    gather_kernel<<<NN / 4, 256, 0, stream>>>(rowptr, pt, e_vals, edge_attr,
                                              Wv, bv, out, attn_out);
}

// Round 7
// 414.622 us; speedup vs baseline: 1.6538x; 1.4071x over previous
//
#include <hip/hip_runtime.h>
#include <stdint.h>

#define NN 100000
#define NE 1000000
#define NTILES (NE / 64)
#define NB_SCAN 391  // ceil(NN/256)

typedef __attribute__((ext_vector_type(8))) short bf16x8;
typedef __attribute__((ext_vector_type(4))) float f32x4;

// ws layout (bytes)
static const size_t OFF_W1K   = 0;                    // 128*32 bf16 (8 KB)
static const size_t OFF_W1BP  = 8192;                 // 128*128 bf16 (32 KB)
static const size_t OFF_MTB   = 40960;                // 128*128 bf16 (32 KB)
static const size_t OFF_RP    = 73728;                // (NN+1) int rowptr
static const size_t OFF_CUR   = 524288;               // NN int cursor
static const size_t OFF_PART  = 1048576;              // NB_SCAN*256 int
static const size_t OFF_BSUM  = 1572864;              // NB_SCAN int
static const size_t OFF_BSUMX = 1576960;              // NB_SCAN int
static const size_t OFF_CNT   = 1581056;              // NN int histogram
static const size_t OFF_PT    = 2097152;              // NE int2 {edge, tgt} sorted (8 MB)
static const size_t OFF_EVALS = 10485760;             // NE f32 (sorted order)
static const size_t OFF_SNODE = 1u << 24;             // NN*128 bf16 (25.6 MB)

__device__ inline unsigned short f2bf(float f) {
    const unsigned int u = __float_as_uint(f);
    return (unsigned short)((u + 0x7fffu + ((u >> 16) & 1u)) >> 16);  // RNE
}

// ---------------------------------------------------------------------------
// prep: w1k = bf16(Wk) K-padded to 32; w1bp = W1b slot-permuted bf16;
// mtb[i][l] = bf16((W1a@Wq)[i][l]).
// ---------------------------------------------------------------------------
__global__ __launch_bounds__(128) void prep_kernel(
    const float* __restrict__ W1, const float* __restrict__ Wq,
    const float* __restrict__ Wk,
    unsigned short* __restrict__ w1k, unsigned short* __restrict__ w1bp,
    unsigned short* __restrict__ mtb)
{
    const int l = blockIdx.x;   // 0..127
    const int i = threadIdx.x;  // 0..127
    float acc = 0.f;
#pragma unroll 8
    for (int j = 0; j < 128; ++j)
        acc = fmaf(W1[i * 256 + j], Wq[j * 128 + l], acc);
    mtb[i * 128 + l] = f2bf(acc);
    if (i < 32)
        w1k[l * 32 + i] = (i < 10) ? f2bf(Wk[l * 10 + i]) : (unsigned short)0;
    const int m = l;
    const int j = (m & ~31) + 16 * ((m >> 2) & 1) + 4 * ((m >> 3) & 3) + (m & 3);
    w1bp[i * 128 + m] = f2bf(W1[i * 256 + 128 + j]);
}

// ---------------------------------------------------------------------------
// node scores via MFMA: s_node[n][i] = bf16( x[n]@M^T + b1 )
// ---------------------------------------------------------------------------
__global__ __launch_bounds__(256) void node_score_kernel(
    const float* __restrict__ x, const unsigned short* __restrict__ mtb_g,
    const float* __restrict__ b1, unsigned short* __restrict__ s_node)
{
    __shared__ __align__(16) unsigned short mt_s[128 * 136];
    const int t = threadIdx.x;
    for (int idx = t; idx < 2048; idx += 256) {
        const uint4 v = ((const uint4*)mtb_g)[idx];
        const int row = idx >> 4, q = idx & 15;
        *(uint4*)&mt_s[row * 136 + q * 8] = v;
    }
    __syncthreads();

    const int lane = t & 63;
    const int wave = t >> 6;
    const int h    = lane >> 4;
    const int e15  = lane & 15;
    const int node = blockIdx.x * 64 + wave * 16 + e15;
    const int nc   = min(node, NN - 1);
    const int lds_base = e15 * 136 + h * 8;

    const f32x4 z4 = {0.f, 0.f, 0.f, 0.f};
    f32x4 acc[8];
#pragma unroll
    for (int g = 0; g < 8; ++g) acc[g] = z4;

#pragma unroll
    for (int s = 0; s < 4; ++s) {
        const float4 xa = *(const float4*)&x[(size_t)nc * 128 + s * 32 + h * 8];
        const float4 xb = *(const float4*)&x[(size_t)nc * 128 + s * 32 + h * 8 + 4];
        bf16x8 bx;
        bx[0] = (short)f2bf(xa.x); bx[1] = (short)f2bf(xa.y);
        bx[2] = (short)f2bf(xa.z); bx[3] = (short)f2bf(xa.w);
        bx[4] = (short)f2bf(xb.x); bx[5] = (short)f2bf(xb.y);
        bx[6] = (short)f2bf(xb.z); bx[7] = (short)f2bf(xb.w);
#pragma unroll
        for (int g = 0; g < 8; ++g) {
            const bf16x8 a = *(const bf16x8*)&mt_s[lds_base + g * (16 * 136) + s * 32];
            acc[g] = __builtin_amdgcn_mfma_f32_16x16x32_bf16(a, bx, acc[g], 0, 0, 0);
        }
    }

    if (node < NN) {
#pragma unroll
        for (int g = 0; g < 8; ++g) {
            const float4 bb = *(const float4*)&b1[g * 16 + h * 4];
            ushort4 o4;
            o4.x = f2bf(acc[g][0] + bb.x);
            o4.y = f2bf(acc[g][1] + bb.y);
            o4.z = f2bf(acc[g][2] + bb.z);
            o4.w = f2bf(acc[g][3] + bb.w);
            *(ushort4*)&s_node[(size_t)node * 128 + g * 16 + h * 4] = o4;
        }
    }
}

// ---------------------------------------------------------------------------
// CSR build: histogram -> block scan -> fill {edge,tgt} pairs in sorted order
// ---------------------------------------------------------------------------
__global__ __launch_bounds__(256) void hist_kernel(
    const int* __restrict__ tgt, int* __restrict__ cnt)
{
    const int e = blockIdx.x * 256 + threadIdx.x;
    if (e < NE) atomicAdd(&cnt[tgt[e]], 1);
}

__global__ __launch_bounds__(256) void scan1_kernel(
    const int* __restrict__ cnt, int* __restrict__ part, int* __restrict__ bsum)
{
    __shared__ int s[256];
    const int t = threadIdx.x;
    const int idx = blockIdx.x * 256 + t;
    const int v = (idx < NN) ? cnt[idx] : 0;
    s[t] = v;
    __syncthreads();
    for (int off = 1; off < 256; off <<= 1) {
        const int u = (t >= off) ? s[t - off] : 0;
        __syncthreads();
        s[t] += u;
        __syncthreads();
    }
    part[idx] = s[t] - v;  // exclusive
    if (t == 255) bsum[blockIdx.x] = s[255];
}

__global__ __launch_bounds__(512) void scan2_kernel(
    const int* __restrict__ bsum, int* __restrict__ bsumx)
{
    __shared__ int s[512];
    const int t = threadIdx.x;
    const int v = (t < NB_SCAN) ? bsum[t] : 0;
    s[t] = v;
    __syncthreads();
    for (int off = 1; off < 512; off <<= 1) {
        const int u = (t >= off) ? s[t - off] : 0;
        __syncthreads();
        s[t] += u;
        __syncthreads();
    }
    if (t < NB_SCAN) bsumx[t] = s[t] - v;  // exclusive
}

__global__ __launch_bounds__(256) void scan3_kernel(
    const int* __restrict__ part, const int* __restrict__ bsumx,
    int* __restrict__ rowptr, int* __restrict__ cursor)
{
    const int idx = blockIdx.x * 256 + threadIdx.x;
    if (idx < NN) {
        const int rp = part[idx] + bsumx[idx >> 8];
        rowptr[idx] = rp;
        cursor[idx] = rp;
    }
    if (idx == 0) rowptr[NN] = NE;
}

__global__ __launch_bounds__(256) void fill_kernel(
    const int* __restrict__ tgt, int* __restrict__ cursor, int2* __restrict__ pt)
{
    const int e = blockIdx.x * 256 + threadIdx.x;
    if (e < NE) {
        const int tg = tgt[e];
        const int p  = atomicAdd(&cursor[tg], 1);
        pt[p] = make_int2(e, tg);
    }
}

// ---------------------------------------------------------------------------
// edge scores via MFMA, CSR-sorted order (s_node reads L1/L2-hit).
// NO launch_bounds floor: R5/R6 showed forcing the unified VGPR/AGPR budget
// below ~130 spills to scratch (WRITE_SIZE 98-156 MB). Let the allocator
// land naturally (~124 with the 2-acc phase-2 structure).
// ---------------------------------------------------------------------------
__global__ __launch_bounds__(256) void edge_kernel(
    const float* __restrict__ edge_attr, const int2* __restrict__ pt,
    const unsigned short* __restrict__ w1k_g, const unsigned short* __restrict__ w1bp_g,
    const float* __restrict__ W2, const float* __restrict__ b2,
    const unsigned short* __restrict__ s_node,
    float* __restrict__ e_vals)
{
    __shared__ __align__(16) unsigned short w1b_s[128 * 136];

    const int t = threadIdx.x;
    for (int idx = t; idx < 2048; idx += 256) {
        const uint4 v = ((const uint4*)w1bp_g)[idx];
        const int row = idx >> 4, q = idx & 15;
        *(uint4*)&w1b_s[row * 136 + q * 8] = v;
    }

    const int lane = t & 63;
    const int wave = t >> 6;
    const int h    = lane >> 4;
    const int e15  = lane & 15;

    bf16x8 a1[8];
#pragma unroll
    for (int f = 0; f < 8; ++f)
        a1[f] = *(const bf16x8*)&w1k_g[(f * 16 + e15) * 32 + h * 8];
    const float b2v = b2[0];

    __syncthreads();

    const int lds_base = e15 * 136 + h * 8;
    const int cstep    = gridDim.x * 64;

    int c = blockIdx.x * 64 + wave * 16 + e15;  // sorted edge index
    int2 ptc = pt[min(c, NE - 1)];

    for (int tile = blockIdx.x; tile < NTILES; tile += gridDim.x, c += cstep) {
        const int ee = ptc.x;   // original edge id (for edge_attr)
        const int tg = ptc.y;   // target node

        // s_node row read — sorted order makes these mostly L1/L2 hits
        uint2 sn[8];
#pragma unroll
        for (int g = 0; g < 8; ++g)
            sn[g] = *(const uint2*)&s_node[(size_t)tg * 128 + g * 16 + h * 4];

        // prefetch next tile's {edge,tgt}
        if (tile + (int)gridDim.x < NTILES) ptc = pt[c + cstep];

        // B1 frag: edge_attr channels (gathered via ee)
        bf16x8 b1 = (bf16x8){0, 0, 0, 0, 0, 0, 0, 0};
        const float* pa = edge_attr + (size_t)ee * 10;
        if (h == 0) {
            const float2 u0 = *(const float2*)(pa + 0);
            const float2 u1 = *(const float2*)(pa + 2);
            const float2 u2 = *(const float2*)(pa + 4);
            const float2 u3 = *(const float2*)(pa + 6);
            b1[0] = (short)f2bf(u0.x); b1[1] = (short)f2bf(u0.y);
            b1[2] = (short)f2bf(u1.x); b1[3] = (short)f2bf(u1.y);
            b1[4] = (short)f2bf(u2.x); b1[5] = (short)f2bf(u2.y);
            b1[6] = (short)f2bf(u3.x); b1[7] = (short)f2bf(u3.y);
        } else if (h == 1) {
            const float2 u4 = *(const float2*)(pa + 8);
            b1[0] = (short)f2bf(u4.x); b1[1] = (short)f2bf(u4.y);
        }

        // phase 1: k[j][e], j = 16f + 4h + r
        const f32x4 z4 = {0.f, 0.f, 0.f, 0.f};
        f32x4 acc1[8];
#pragma unroll
        for (int f = 0; f < 8; ++f)
            acc1[f] = __builtin_amdgcn_mfma_f32_16x16x32_bf16(a1[f], b1, z4, 0, 0, 0);

        // pack all 4 B-frags (acc1 dies here)
        bf16x8 pb[4];
#pragma unroll
        for (int s = 0; s < 4; ++s) {
#pragma unroll
            for (int e8 = 0; e8 < 8; ++e8) {
                float v = acc1[2 * s + (e8 >> 2)][e8 & 3];
                v = (v >= 0.f) ? v : 0.01f * v;
                pb[s][e8] = (short)f2bf(v);
            }
        }

        // phase 2 g-outer (pairs), epilogue folded per pair: acc2 = 2 x f32x4
        float p = 0.f;
#pragma unroll
        for (int g2 = 0; g2 < 4; ++g2) {
            const int gA = 2 * g2, gB = 2 * g2 + 1;
            f32x4 accA = z4, accB = z4;
#pragma unroll
            for (int s = 0; s < 4; ++s) {
                const bf16x8 a2A = *(const bf16x8*)&w1b_s[lds_base + gA * (16 * 136) + s * 32];
                const bf16x8 a2B = *(const bf16x8*)&w1b_s[lds_base + gB * (16 * 136) + s * 32];
                accA = __builtin_amdgcn_mfma_f32_16x16x32_bf16(a2A, pb[s], accA, 0, 0, 0);
                accB = __builtin_amdgcn_mfma_f32_16x16x32_bf16(a2B, pb[s], accB, 0, 0, 0);
            }
            const float4 w2A = *(const float4*)&W2[gA * 16 + h * 4];
            const float4 w2B = *(const float4*)&W2[gB * 16 + h * 4];
            const uint2 svA = sn[gA], svB = sn[gB];
            p = fmaf(fmaxf(accA[0] + __uint_as_float(svA.x << 16), 0.f), w2A.x, p);
            p = fmaf(fmaxf(accA[1] + __uint_as_float(svA.x & 0xffff0000u), 0.f), w2A.y, p);
            p = fmaf(fmaxf(accA[2] + __uint_as_float(svA.y << 16), 0.f), w2A.z, p);
            p = fmaf(fmaxf(accA[3] + __uint_as_float(svA.y & 0xffff0000u), 0.f), w2A.w, p);
            p = fmaf(fmaxf(accB[0] + __uint_as_float(svB.x << 16), 0.f), w2B.x, p);
            p = fmaf(fmaxf(accB[1] + __uint_as_float(svB.x & 0xffff0000u), 0.f), w2B.y, p);
            p = fmaf(fmaxf(accB[2] + __uint_as_float(svB.y << 16), 0.f), w2B.z, p);
            p = fmaf(fmaxf(accB[3] + __uint_as_float(svB.y & 0xffff0000u), 0.f), w2B.w, p);
        }
        p += __shfl_xor(p, 16);
        p += __shfl_xor(p, 32);
        if (lane < 16)
            e_vals[c - e15 + lane] = expf(p + b2v);  // sorted index, coalesced
    }
}

// ---------------------------------------------------------------------------
// gather: one wave per node. Phase B: each lane PRE-GATHERS its own edge's
// 10-float edge_attr row (parallel, 5x float2), then the per-edge loop
// broadcasts via __shfl (VALU) — no serial memory latency in the chain.
// ---------------------------------------------------------------------------
__global__ __launch_bounds__(256) void gather_kernel(
    const int* __restrict__ rowptr, const int2* __restrict__ pt,
    const float* __restrict__ e_vals, const float* __restrict__ edge_attr,
    const float* __restrict__ Wv, const float* __restrict__ bv,
    float* __restrict__ out, float* __restrict__ attn_out)
{
    const int t    = threadIdx.x;
    const int lane = t & 63;
    const int wave = t >> 6;
    const int node = blockIdx.x * 4 + wave;
    const int d0   = lane * 2;

    float wv0[10], wv1[10];
#pragma unroll
    for (int c = 0; c < 10; ++c) {
        wv0[c] = Wv[d0 * 10 + c];
        wv1[c] = Wv[d0 * 10 + 10 + c];
    }
    const float bv0 = bv[d0], bv1 = bv[d0 + 1];

    const int start = rowptr[node];
    const int end   = rowptr[node + 1];

    // phase A: denominator (coalesced e_vals)
    float part = 0.f;
    for (int c = start + lane; c < end; c += 64) part += e_vals[c];
    part += __shfl_xor(part, 1);
    part += __shfl_xor(part, 2);
    part += __shfl_xor(part, 4);
    part += __shfl_xor(part, 8);
    part += __shfl_xor(part, 16);
    part += __shfl_xor(part, 32);
    const float inv = 1.f / (part + 1e-16f);

    float acc0 = 0.f, acc1 = 0.f;
    for (int c0 = start; c0 < end; c0 += 64) {
        const int m = min(64, end - c0);
        float r0 = 0.f, r1 = 0.f, r2 = 0.f, r3 = 0.f, r4 = 0.f;
        float r5 = 0.f, r6 = 0.f, r7 = 0.f, r8 = 0.f, r9 = 0.f;
        float evl = 0.f;
        if (lane < m) {
            const int ee = pt[c0 + lane].x;
            evl = e_vals[c0 + lane];
            attn_out[ee] = evl * inv;
            const float* pa = edge_attr + (size_t)ee * 10;
            const float2 u0 = *(const float2*)(pa + 0);
            const float2 u1 = *(const float2*)(pa + 2);
            const float2 u2 = *(const float2*)(pa + 4);
            const float2 u3 = *(const float2*)(pa + 6);
            const float2 u4 = *(const float2*)(pa + 8);
            r0 = u0.x; r1 = u0.y; r2 = u1.x; r3 = u1.y; r4 = u2.x;
            r5 = u2.y; r6 = u3.x; r7 = u3.y; r8 = u4.x; r9 = u4.y;
        }
#pragma unroll 2
        for (int d = 0; d < m; ++d) {
            const float ad = __shfl(evl, d) * inv;
            const float c0v = __shfl(r0, d), c1v = __shfl(r1, d);
            const float c2v = __shfl(r2, d), c3v = __shfl(r3, d);
            const float c4v = __shfl(r4, d), c5v = __shfl(r5, d);
            const float c6v = __shfl(r6, d), c7v = __shfl(r7, d);
            const float c8v = __shfl(r8, d), c9v = __shfl(r9, d);
            float a0 = bv0, a1 = bv1;
            a0 = fmaf(c0v, wv0[0], a0); a1 = fmaf(c0v, wv1[0], a1);
            a0 = fmaf(c1v, wv0[1], a0); a1 = fmaf(c1v, wv1[1], a1);
            a0 = fmaf(c2v, wv0[2], a0); a1 = fmaf(c2v, wv1[2], a1);
            a0 = fmaf(c3v, wv0[3], a0); a1 = fmaf(c3v, wv1[3], a1);
            a0 = fmaf(c4v, wv0[4], a0); a1 = fmaf(c4v, wv1[4], a1);
            a0 = fmaf(c5v, wv0[5], a0); a1 = fmaf(c5v, wv1[5], a1);
            a0 = fmaf(c6v, wv0[6], a0); a1 = fmaf(c6v, wv1[6], a1);
            a0 = fmaf(c7v, wv0[7], a0); a1 = fmaf(c7v, wv1[7], a1);
            a0 = fmaf(c8v, wv0[8], a0); a1 = fmaf(c8v, wv1[8], a1);
            a0 = fmaf(c9v, wv0[9], a0); a1 = fmaf(c9v, wv1[9], a1);
            const float v0 = (a0 >= 0.f) ? a0 : 0.01f * a0;
            const float v1 = (a1 >= 0.f) ? a1 : 0.01f * a1;
            acc0 = fmaf(ad, v0, acc0);
            acc1 = fmaf(ad, v1, acc1);
        }
    }
    *(float2*)&out[(size_t)node * 128 + d0] = make_float2(acc0, acc1);
}

extern "C" void kernel_launch(void* const* d_in, const int* in_sizes, int n_in,
                              void* d_out, int out_size, void* d_ws, size_t ws_size,
                              hipStream_t stream)
{
    const float* x         = (const float*)d_in[0];
    const int*   eidx      = (const int*)d_in[1];
    const float* edge_attr = (const float*)d_in[2];
    const float* Wq        = (const float*)d_in[3];
    const float* Wk        = (const float*)d_in[4];
    const float* Wv        = (const float*)d_in[5];
    const float* bv        = (const float*)d_in[6];
    const float* W1        = (const float*)d_in[7];
    const float* b1        = (const float*)d_in[8];
    const float* W2        = (const float*)d_in[9];
    const float* b2        = (const float*)d_in[10];
    const int*   tgt       = eidx + NE;  // edge_index[1]

    char* ws = (char*)d_ws;
    unsigned short* w1k    = (unsigned short*)(ws + OFF_W1K);
    unsigned short* w1bp   = (unsigned short*)(ws + OFF_W1BP);
    unsigned short* mtb    = (unsigned short*)(ws + OFF_MTB);
    int*            rowptr = (int*)(ws + OFF_RP);
    int*            cursor = (int*)(ws + OFF_CUR);
    int*            part   = (int*)(ws + OFF_PART);
    int*            bsum   = (int*)(ws + OFF_BSUM);
    int*            bsumx  = (int*)(ws + OFF_BSUMX);
    int*            cnt    = (int*)(ws + OFF_CNT);
    int2*           pt     = (int2*)(ws + OFF_PT);
    float*          e_vals = (float*)(ws + OFF_EVALS);
    unsigned short* s_node = (unsigned short*)(ws + OFF_SNODE);

    float* out      = (float*)d_out;
    float* attn_out = out + (size_t)NN * 128;

    hipMemsetAsync(cnt, 0, (size_t)NN * sizeof(int), stream);

    prep_kernel<<<128, 128, 0, stream>>>(W1, Wq, Wk, w1k, w1bp, mtb);
    node_score_kernel<<<(NN + 63) / 64, 256, 0, stream>>>(x, mtb, b1, s_node);
    hist_kernel<<<(NE + 255) / 256, 256, 0, stream>>>(tgt, cnt);
    scan1_kernel<<<NB_SCAN, 256, 0, stream>>>(cnt, part, bsum);
    scan2_kernel<<<1, 512, 0, stream>>>(bsum, bsumx);
    scan3_kernel<<<NB_SCAN, 256, 0, stream>>>(part, bsumx, rowptr, cursor);
    fill_kernel<<<(NE + 255) / 256, 256, 0, stream>>>(tgt, cursor, pt);
    edge_kernel<<<1024, 256, 0, stream>>>(edge_attr, pt, w1k, w1bp, W2, b2,
                                          s_node, e_vals);
    gather_kernel<<<NN / 4, 256, 0, stream>>>(rowptr, pt, e_vals, edge_attr,
                                              Wv, bv, out, attn_out);
}

// Round 8
// 353.266 us; speedup vs baseline: 1.9410x; 1.1737x over previous
//
#include <hip/hip_runtime.h>
#include <stdint.h>

#define NN 100000
#define NE 1000000
#define NTILES (NE / 64)
#define NB_SCAN 391  // ceil(NN/256)

typedef __attribute__((ext_vector_type(8))) short bf16x8;
typedef __attribute__((ext_vector_type(4))) float f32x4;

// ws layout (bytes)
static const size_t OFF_W1K   = 0;                    // 128*32 bf16 (8 KB)
static const size_t OFF_W1BP  = 8192;                 // 128*128 bf16 (32 KB)
static const size_t OFF_MTB   = 40960;                // 128*128 bf16 (32 KB)
static const size_t OFF_RP    = 73728;                // (NN+1) int rowptr
static const size_t OFF_CUR   = 524288;               // NN int cursor
static const size_t OFF_PART  = 1048576;              // NB_SCAN*256 int
static const size_t OFF_BSUM  = 1572864;              // NB_SCAN int
static const size_t OFF_BSUMX = 1576960;              // NB_SCAN int
static const size_t OFF_CNT   = 1581056;              // NN int histogram
static const size_t OFF_PT    = 2097152;              // NE int2 {edge, tgt} sorted (8 MB)
static const size_t OFF_EVALS = 10485760;             // NE f32 (sorted order, 4 MB)
static const size_t OFF_EAS   = 14485760;             // NE * 5 uint (bf16x10 packed, 20 MB)
static const size_t OFF_SNODE = 34485760;             // NN*128 bf16 (25.6 MB) -> total ~60 MB

__device__ inline unsigned short f2bf(float f) {
    const unsigned int u = __float_as_uint(f);
    return (unsigned short)((u + 0x7fffu + ((u >> 16) & 1u)) >> 16);  // RNE
}

__device__ inline unsigned int cvtpk(float lo, float hi) {
    unsigned int r;
    asm("v_cvt_pk_bf16_f32 %0, %1, %2" : "=v"(r) : "v"(lo), "v"(hi));
    return r;  // [15:0]=bf16(lo), [31:16]=bf16(hi), RNE
}

__device__ inline float lk(float v) {  // leaky_relu 0.01
    return fmaxf(v, 0.f) + 0.01f * fminf(v, 0.f);
}

union BU { bf16x8 v; uint4 u; };

// ---------------------------------------------------------------------------
// prep: w1k = bf16(Wk) K-padded to 32; w1bp = W1b slot-permuted bf16;
// mtb[i][l] = bf16((W1a@Wq)[i][l]).
// ---------------------------------------------------------------------------
__global__ __launch_bounds__(128) void prep_kernel(
    const float* __restrict__ W1, const float* __restrict__ Wq,
    const float* __restrict__ Wk,
    unsigned short* __restrict__ w1k, unsigned short* __restrict__ w1bp,
    unsigned short* __restrict__ mtb)
{
    const int l = blockIdx.x;   // 0..127
    const int i = threadIdx.x;  // 0..127
    float acc = 0.f;
#pragma unroll 8
    for (int j = 0; j < 128; ++j)
        acc = fmaf(W1[i * 256 + j], Wq[j * 128 + l], acc);
    mtb[i * 128 + l] = f2bf(acc);
    if (i < 32)
        w1k[l * 32 + i] = (i < 10) ? f2bf(Wk[l * 10 + i]) : (unsigned short)0;
    const int m = l;
    const int j = (m & ~31) + 16 * ((m >> 2) & 1) + 4 * ((m >> 3) & 3) + (m & 3);
    w1bp[i * 128 + m] = f2bf(W1[i * 256 + 128 + j]);
}

// ---------------------------------------------------------------------------
// node scores via MFMA: s_node[n][i] = bf16( x[n]@M^T + b1 )
// ---------------------------------------------------------------------------
__global__ __launch_bounds__(256) void node_score_kernel(
    const float* __restrict__ x, const unsigned short* __restrict__ mtb_g,
    const float* __restrict__ b1, unsigned short* __restrict__ s_node)
{
    __shared__ __align__(16) unsigned short mt_s[128 * 136];
    const int t = threadIdx.x;
    for (int idx = t; idx < 2048; idx += 256) {
        const uint4 v = ((const uint4*)mtb_g)[idx];
        const int row = idx >> 4, q = idx & 15;
        *(uint4*)&mt_s[row * 136 + q * 8] = v;
    }
    __syncthreads();

    const int lane = t & 63;
    const int wave = t >> 6;
    const int h    = lane >> 4;
    const int e15  = lane & 15;
    const int node = blockIdx.x * 64 + wave * 16 + e15;
    const int nc   = min(node, NN - 1);
    const int lds_base = e15 * 136 + h * 8;

    const f32x4 z4 = {0.f, 0.f, 0.f, 0.f};
    f32x4 acc[8];
#pragma unroll
    for (int g = 0; g < 8; ++g) acc[g] = z4;

#pragma unroll
    for (int s = 0; s < 4; ++s) {
        const float4 xa = *(const float4*)&x[(size_t)nc * 128 + s * 32 + h * 8];
        const float4 xb = *(const float4*)&x[(size_t)nc * 128 + s * 32 + h * 8 + 4];
        BU bx;
        bx.u.x = cvtpk(xa.x, xa.y);
        bx.u.y = cvtpk(xa.z, xa.w);
        bx.u.z = cvtpk(xb.x, xb.y);
        bx.u.w = cvtpk(xb.z, xb.w);
#pragma unroll
        for (int g = 0; g < 8; ++g) {
            const bf16x8 a = *(const bf16x8*)&mt_s[lds_base + g * (16 * 136) + s * 32];
            acc[g] = __builtin_amdgcn_mfma_f32_16x16x32_bf16(a, bx.v, acc[g], 0, 0, 0);
        }
    }

    if (node < NN) {
#pragma unroll
        for (int g = 0; g < 8; ++g) {
            const float4 bb = *(const float4*)&b1[g * 16 + h * 4];
            uint2 o2;
            o2.x = cvtpk(acc[g][0] + bb.x, acc[g][1] + bb.y);
            o2.y = cvtpk(acc[g][2] + bb.z, acc[g][3] + bb.w);
            *(uint2*)&s_node[(size_t)node * 128 + g * 16 + h * 4] = o2;
        }
    }
}

// ---------------------------------------------------------------------------
// CSR build: histogram -> block scan -> fill {edge,tgt} pairs in sorted order
// ---------------------------------------------------------------------------
__global__ __launch_bounds__(256) void hist_kernel(
    const int* __restrict__ tgt, int* __restrict__ cnt)
{
    const int e = blockIdx.x * 256 + threadIdx.x;
    if (e < NE) atomicAdd(&cnt[tgt[e]], 1);
}

__global__ __launch_bounds__(256) void scan1_kernel(
    const int* __restrict__ cnt, int* __restrict__ part, int* __restrict__ bsum)
{
    __shared__ int s[256];
    const int t = threadIdx.x;
    const int idx = blockIdx.x * 256 + t;
    const int v = (idx < NN) ? cnt[idx] : 0;
    s[t] = v;
    __syncthreads();
    for (int off = 1; off < 256; off <<= 1) {
        const int u = (t >= off) ? s[t - off] : 0;
        __syncthreads();
        s[t] += u;
        __syncthreads();
    }
    part[idx] = s[t] - v;  // exclusive
    if (t == 255) bsum[blockIdx.x] = s[255];
}

__global__ __launch_bounds__(512) void scan2_kernel(
    const int* __restrict__ bsum, int* __restrict__ bsumx)
{
    __shared__ int s[512];
    const int t = threadIdx.x;
    const int v = (t < NB_SCAN) ? bsum[t] : 0;
    s[t] = v;
    __syncthreads();
    for (int off = 1; off < 512; off <<= 1) {
        const int u = (t >= off) ? s[t - off] : 0;
        __syncthreads();
        s[t] += u;
        __syncthreads();
    }
    if (t < NB_SCAN) bsumx[t] = s[t] - v;  // exclusive
}

__global__ __launch_bounds__(256) void scan3_kernel(
    const int* __restrict__ part, const int* __restrict__ bsumx,
    int* __restrict__ rowptr, int* __restrict__ cursor)
{
    const int idx = blockIdx.x * 256 + threadIdx.x;
    if (idx < NN) {
        const int rp = part[idx] + bsumx[idx >> 8];
        rowptr[idx] = rp;
        cursor[idx] = rp;
    }
    if (idx == 0) rowptr[NN] = NE;
}

__global__ __launch_bounds__(256) void fill_kernel(
    const int* __restrict__ tgt, int* __restrict__ cursor, int2* __restrict__ pt)
{
    const int e = blockIdx.x * 256 + threadIdx.x;
    if (e < NE) {
        const int tg = tgt[e];
        const int p  = atomicAdd(&cursor[tg], 1);
        pt[p] = make_int2(e, tg);
    }
}

// ---------------------------------------------------------------------------
// edge scores via MFMA, CSR-sorted, 2-deep software pipeline:
// tile t computes while tile t+1's s_node row + edge_attr are in flight
// (and pt for t+2). Also emits ea_sorted (bf16-packed, 5 uints/edge) reusing
// the b1 conversion registers, so gather reads edge_attr coalesced.
// ---------------------------------------------------------------------------
__global__ __launch_bounds__(256) void edge_kernel(
    const float* __restrict__ edge_attr, const int2* __restrict__ pt,
    const unsigned short* __restrict__ w1k_g, const unsigned short* __restrict__ w1bp_g,
    const float* __restrict__ W2, const float* __restrict__ b2,
    const unsigned short* __restrict__ s_node,
    float* __restrict__ e_vals, unsigned int* __restrict__ eas)
{
    __shared__ __align__(16) unsigned short w1b_s[128 * 136];

    const int t = threadIdx.x;
    for (int idx = t; idx < 2048; idx += 256) {
        const uint4 v = ((const uint4*)w1bp_g)[idx];
        const int row = idx >> 4, q = idx & 15;
        *(uint4*)&w1b_s[row * 136 + q * 8] = v;
    }

    const int lane = t & 63;
    const int wave = t >> 6;
    const int h    = lane >> 4;
    const int e15  = lane & 15;

    bf16x8 a1[8];
#pragma unroll
    for (int f = 0; f < 8; ++f)
        a1[f] = *(const bf16x8*)&w1k_g[(f * 16 + e15) * 32 + h * 8];
    const float b2v = b2[0];

    __syncthreads();

    const int lds_base = e15 * 136 + h * 8;
    const int cstep    = gridDim.x * 64;

    int c = blockIdx.x * 64 + wave * 16 + e15;  // sorted edge index

    // ---- pipeline prologue: tile-0 data + tile-1 pt ----
    int2 ptc = pt[min(c, NE - 1)];
    int2 ptn = pt[min(c + cstep, NE - 1)];

    uint2 sn[8];
#pragma unroll
    for (int g = 0; g < 8; ++g)
        sn[g] = *(const uint2*)&s_node[(size_t)ptc.y * 128 + g * 16 + h * 4];

    float ea0 = 0.f, ea1 = 0.f, ea2 = 0.f, ea3 = 0.f, ea4 = 0.f;
    float ea5 = 0.f, ea6 = 0.f, ea7 = 0.f, ea8 = 0.f, ea9 = 0.f;
    {
        const float* pa = edge_attr + (size_t)ptc.x * 10;
        if (h == 0) {
            const float2 u0 = *(const float2*)(pa + 0);
            const float2 u1 = *(const float2*)(pa + 2);
            const float2 u2 = *(const float2*)(pa + 4);
            const float2 u3 = *(const float2*)(pa + 6);
            ea0 = u0.x; ea1 = u0.y; ea2 = u1.x; ea3 = u1.y;
            ea4 = u2.x; ea5 = u2.y; ea6 = u3.x; ea7 = u3.y;
        } else if (h == 1) {
            const float2 u4 = *(const float2*)(pa + 8);
            ea8 = u4.x; ea9 = u4.y;
        }
    }

    for (int tile = blockIdx.x; tile < NTILES; tile += gridDim.x, c += cstep) {
        // ---- issue next-tile prefetches (hide under this tile's compute) ----
        const int2 ptn2 = pt[min(c + 2 * cstep, NE - 1)];
        uint2 sn_n[8];
#pragma unroll
        for (int g = 0; g < 8; ++g)
            sn_n[g] = *(const uint2*)&s_node[(size_t)ptn.y * 128 + g * 16 + h * 4];
        float en0 = 0.f, en1 = 0.f, en2 = 0.f, en3 = 0.f, en4 = 0.f;
        float en5 = 0.f, en6 = 0.f, en7 = 0.f, en8 = 0.f, en9 = 0.f;
        {
            const float* pa = edge_attr + (size_t)ptn.x * 10;
            if (h == 0) {
                const float2 u0 = *(const float2*)(pa + 0);
                const float2 u1 = *(const float2*)(pa + 2);
                const float2 u2 = *(const float2*)(pa + 4);
                const float2 u3 = *(const float2*)(pa + 6);
                en0 = u0.x; en1 = u0.y; en2 = u1.x; en3 = u1.y;
                en4 = u2.x; en5 = u2.y; en6 = u3.x; en7 = u3.y;
            } else if (h == 1) {
                const float2 u4 = *(const float2*)(pa + 8);
                en8 = u4.x; en9 = u4.y;
            }
        }

        // ---- B1 pack (cvt_pk) + ea_sorted store from the same registers ----
        bf16x8 b1 = (bf16x8){0, 0, 0, 0, 0, 0, 0, 0};
        {
            unsigned int* po = eas + (size_t)c * 5;
            if (h == 0) {
                BU bu;
                bu.u.x = cvtpk(ea0, ea1);
                bu.u.y = cvtpk(ea2, ea3);
                bu.u.z = cvtpk(ea4, ea5);
                bu.u.w = cvtpk(ea6, ea7);
                b1 = bu.v;
                po[0] = bu.u.x; po[1] = bu.u.y; po[2] = bu.u.z; po[3] = bu.u.w;
            } else if (h == 1) {
                BU bu;
                bu.u.x = cvtpk(ea8, ea9);
                bu.u.y = 0; bu.u.z = 0; bu.u.w = 0;
                b1 = bu.v;
                po[4] = bu.u.x;
            }
        }

        // ---- phase 1: k[j][e], j = 16f + 4h + r ----
        const f32x4 z4 = {0.f, 0.f, 0.f, 0.f};
        f32x4 acc1[8];
#pragma unroll
        for (int f = 0; f < 8; ++f)
            acc1[f] = __builtin_amdgcn_mfma_f32_16x16x32_bf16(a1[f], b1, z4, 0, 0, 0);

        // ---- leaky + pack (cvt_pk), acc1 dies ----
        bf16x8 pb[4];
#pragma unroll
        for (int s = 0; s < 4; ++s) {
            BU bu;
            bu.u.x = cvtpk(lk(acc1[2 * s][0]), lk(acc1[2 * s][1]));
            bu.u.y = cvtpk(lk(acc1[2 * s][2]), lk(acc1[2 * s][3]));
            bu.u.z = cvtpk(lk(acc1[2 * s + 1][0]), lk(acc1[2 * s + 1][1]));
            bu.u.w = cvtpk(lk(acc1[2 * s + 1][2]), lk(acc1[2 * s + 1][3]));
            pb[s] = bu.v;
        }

        // ---- phase 2 g-pairs with folded epilogue ----
        float p = 0.f;
#pragma unroll
        for (int g2 = 0; g2 < 4; ++g2) {
            const int gA = 2 * g2, gB = 2 * g2 + 1;
            f32x4 accA = z4, accB = z4;
#pragma unroll
            for (int s = 0; s < 4; ++s) {
                const bf16x8 a2A = *(const bf16x8*)&w1b_s[lds_base + gA * (16 * 136) + s * 32];
                const bf16x8 a2B = *(const bf16x8*)&w1b_s[lds_base + gB * (16 * 136) + s * 32];
                accA = __builtin_amdgcn_mfma_f32_16x16x32_bf16(a2A, pb[s], accA, 0, 0, 0);
                accB = __builtin_amdgcn_mfma_f32_16x16x32_bf16(a2B, pb[s], accB, 0, 0, 0);
            }
            const float4 w2A = *(const float4*)&W2[gA * 16 + h * 4];
            const float4 w2B = *(const float4*)&W2[gB * 16 + h * 4];
            const uint2 svA = sn[gA], svB = sn[gB];
            p = fmaf(fmaxf(accA[0] + __uint_as_float(svA.x << 16), 0.f), w2A.x, p);
            p = fmaf(fmaxf(accA[1] + __uint_as_float(svA.x & 0xffff0000u), 0.f), w2A.y, p);
            p = fmaf(fmaxf(accA[2] + __uint_as_float(svA.y << 16), 0.f), w2A.z, p);
            p = fmaf(fmaxf(accA[3] + __uint_as_float(svA.y & 0xffff0000u), 0.f), w2A.w, p);
            p = fmaf(fmaxf(accB[0] + __uint_as_float(svB.x << 16), 0.f), w2B.x, p);
            p = fmaf(fmaxf(accB[1] + __uint_as_float(svB.x & 0xffff0000u), 0.f), w2B.y, p);
            p = fmaf(fmaxf(accB[2] + __uint_as_float(svB.y << 16), 0.f), w2B.z, p);
            p = fmaf(fmaxf(accB[3] + __uint_as_float(svB.y & 0xffff0000u), 0.f), w2B.w, p);
        }
        p += __shfl_xor(p, 16);
        p += __shfl_xor(p, 32);
        if (lane < 16)
            e_vals[c - e15 + lane] = __expf(p + b2v);  // sorted index, coalesced

        // ---- rotate pipeline ----
        ptc = ptn; ptn = ptn2;
#pragma unroll
        for (int g = 0; g < 8; ++g) sn[g] = sn_n[g];
        ea0 = en0; ea1 = en1; ea2 = en2; ea3 = en3; ea4 = en4;
        ea5 = en5; ea6 = en6; ea7 = en7; ea8 = en8; ea9 = en9;
    }
}

// ---------------------------------------------------------------------------
// gather: one wave per node. Lane pre-gathers its own edge's bf16-packed
// attrs from ea_sorted (COALESCED: contiguous sorted index), then the d-loop
// broadcasts via shfl. One float2 store per node row; no atomics.
// ---------------------------------------------------------------------------
__global__ __launch_bounds__(256) void gather_kernel(
    const int* __restrict__ rowptr, const int2* __restrict__ pt,
    const float* __restrict__ e_vals, const unsigned int* __restrict__ eas,
    const float* __restrict__ Wv, const float* __restrict__ bv,
    float* __restrict__ out, float* __restrict__ attn_out)
{
    const int t    = threadIdx.x;
    const int lane = t & 63;
    const int wave = t >> 6;
    const int node = blockIdx.x * 4 + wave;
    const int d0   = lane * 2;

    float wv0[10], wv1[10];
#pragma unroll
    for (int c = 0; c < 10; ++c) {
        wv0[c] = Wv[d0 * 10 + c];
        wv1[c] = Wv[d0 * 10 + 10 + c];
    }
    const float bv0 = bv[d0], bv1 = bv[d0 + 1];

    const int start = rowptr[node];
    const int end   = rowptr[node + 1];

    // phase A: denominator (coalesced e_vals)
    float part = 0.f;
    for (int c = start + lane; c < end; c += 64) part += e_vals[c];
    part += __shfl_xor(part, 1);
    part += __shfl_xor(part, 2);
    part += __shfl_xor(part, 4);
    part += __shfl_xor(part, 8);
    part += __shfl_xor(part, 16);
    part += __shfl_xor(part, 32);
    const float inv = 1.f / (part + 1e-16f);

    float acc0 = 0.f, acc1 = 0.f;
    for (int c0 = start; c0 < end; c0 += 64) {
        const int m = min(64, end - c0);
        unsigned int w0 = 0, w1 = 0, w2 = 0, w3 = 0, w4 = 0;
        float evl = 0.f;
        if (lane < m) {
            const size_t cc = (size_t)(c0 + lane);
            const int ee = pt[cc].x;
            evl = e_vals[cc];
            attn_out[ee] = evl * inv;
            const unsigned int* pe = eas + cc * 5;
            w0 = pe[0]; w1 = pe[1]; w2 = pe[2]; w3 = pe[3]; w4 = pe[4];
        }
        const float r0 = __uint_as_float(w0 << 16), r1 = __uint_as_float(w0 & 0xffff0000u);
        const float r2 = __uint_as_float(w1 << 16), r3 = __uint_as_float(w1 & 0xffff0000u);
        const float r4 = __uint_as_float(w2 << 16), r5 = __uint_as_float(w2 & 0xffff0000u);
        const float r6 = __uint_as_float(w3 << 16), r7 = __uint_as_float(w3 & 0xffff0000u);
        const float r8 = __uint_as_float(w4 << 16), r9 = __uint_as_float(w4 & 0xffff0000u);
#pragma unroll 2
        for (int d = 0; d < m; ++d) {
            const float ad = __shfl(evl, d) * inv;
            const float c0v = __shfl(r0, d), c1v = __shfl(r1, d);
            const float c2v = __shfl(r2, d), c3v = __shfl(r3, d);
            const float c4v = __shfl(r4, d), c5v = __shfl(r5, d);
            const float c6v = __shfl(r6, d), c7v = __shfl(r7, d);
            const float c8v = __shfl(r8, d), c9v = __shfl(r9, d);
            float a0 = bv0, a1 = bv1;
            a0 = fmaf(c0v, wv0[0], a0); a1 = fmaf(c0v, wv1[0], a1);
            a0 = fmaf(c1v, wv0[1], a0); a1 = fmaf(c1v, wv1[1], a1);
            a0 = fmaf(c2v, wv0[2], a0); a1 = fmaf(c2v, wv1[2], a1);
            a0 = fmaf(c3v, wv0[3], a0); a1 = fmaf(c3v, wv1[3], a1);
            a0 = fmaf(c4v, wv0[4], a0); a1 = fmaf(c4v, wv1[4], a1);
            a0 = fmaf(c5v, wv0[5], a0); a1 = fmaf(c5v, wv1[5], a1);
            a0 = fmaf(c6v, wv0[6], a0); a1 = fmaf(c6v, wv1[6], a1);
            a0 = fmaf(c7v, wv0[7], a0); a1 = fmaf(c7v, wv1[7], a1);
            a0 = fmaf(c8v, wv0[8], a0); a1 = fmaf(c8v, wv1[8], a1);
            a0 = fmaf(c9v, wv0[9], a0); a1 = fmaf(c9v, wv1[9], a1);
            const float v0 = (a0 >= 0.f) ? a0 : 0.01f * a0;
            const float v1 = (a1 >= 0.f) ? a1 : 0.01f * a1;
            acc0 = fmaf(ad, v0, acc0);
            acc1 = fmaf(ad, v1, acc1);
        }
    }
    *(float2*)&out[(size_t)node * 128 + d0] = make_float2(acc0, acc1);
}

extern "C" void kernel_launch(void* const* d_in, const int* in_sizes, int n_in,
                              void* d_out, int out_size, void* d_ws, size_t ws_size,
                              hipStream_t stream)
{
    const float* x         = (const float*)d_in[0];
    const int*   eidx      = (const int*)d_in[1];
    const float* edge_attr = (const float*)d_in[2];
    const float* Wq        = (const float*)d_in[3];
    const float* Wk        = (const float*)d_in[4];
    const float* Wv        = (const float*)d_in[5];
    const float* bv        = (const float*)d_in[6];
    const float* W1        = (const float*)d_in[7];
    const float* b1        = (const float*)d_in[8];
    const float* W2        = (const float*)d_in[9];
    const float* b2        = (const float*)d_in[10];
    const int*   tgt       = eidx + NE;  // edge_index[1]

    char* ws = (char*)d_ws;
    unsigned short* w1k    = (unsigned short*)(ws + OFF_W1K);
    unsigned short* w1bp   = (unsigned short*)(ws + OFF_W1BP);
    unsigned short* mtb    = (unsigned short*)(ws + OFF_MTB);
    int*            rowptr = (int*)(ws + OFF_RP);
    int*            cursor = (int*)(ws + OFF_CUR);
    int*            part   = (int*)(ws + OFF_PART);
    int*            bsum   = (int*)(ws + OFF_BSUM);
    int*            bsumx  = (int*)(ws + OFF_BSUMX);
    int*            cnt    = (int*)(ws + OFF_CNT);
    int2*           pt     = (int2*)(ws + OFF_PT);
    float*          e_vals = (float*)(ws + OFF_EVALS);
    unsigned int*   eas    = (unsigned int*)(ws + OFF_EAS);
    unsigned short* s_node = (unsigned short*)(ws + OFF_SNODE);

    float* out      = (float*)d_out;
    float* attn_out = out + (size_t)NN * 128;

    hipMemsetAsync(cnt, 0, (size_t)NN * sizeof(int), stream);

    prep_kernel<<<128, 128, 0, stream>>>(W1, Wq, Wk, w1k, w1bp, mtb);
    node_score_kernel<<<(NN + 63) / 64, 256, 0, stream>>>(x, mtb, b1, s_node);
    hist_kernel<<<(NE + 255) / 256, 256, 0, stream>>>(tgt, cnt);
    scan1_kernel<<<NB_SCAN, 256, 0, stream>>>(cnt, part, bsum);
    scan2_kernel<<<1, 512, 0, stream>>>(bsum, bsumx);
    scan3_kernel<<<NB_SCAN, 256, 0, stream>>>(part, bsumx, rowptr, cursor);
    fill_kernel<<<(NE + 255) / 256, 256, 0, stream>>>(tgt, cursor, pt);
    edge_kernel<<<768, 256, 0, stream>>>(edge_attr, pt, w1k, w1bp, W2, b2,
                                         s_node, e_vals, eas);
    gather_kernel<<<NN / 4, 256, 0, stream>>>(rowptr, pt, e_vals, eas,
                                              Wv, bv, out, attn_out);
}

// Round 9
// 329.012 us; speedup vs baseline: 2.0841x; 1.0737x over previous
//
#include <hip/hip_runtime.h>
#include <stdint.h>

#define NN 100000
#define NE 1000000
#define NTILES (NE / 64)
#define NB_SCAN 391  // ceil(NN/256)

typedef __attribute__((ext_vector_type(8))) short bf16x8;
typedef __attribute__((ext_vector_type(4))) float f32x4;

// ws layout (bytes)
static const size_t OFF_W1K   = 0;         // 128*32 bf16 (8 KB)
static const size_t OFF_WVK   = 8192;      // 128*32 bf16 (8 KB): Wv K-padded
static const size_t OFF_W1BP  = 16384;     // 128*128 bf16 (32 KB)
static const size_t OFF_MTB   = 49152;     // 128*128 bf16 (32 KB)
static const size_t OFF_RP    = 81920;     // (NN+1) int rowptr
static const size_t OFF_CUR   = 524288;    // NN int cursor; later aliased as inv_denom (f32)
static const size_t OFF_PART  = 1048576;   // NB_SCAN*256 int
static const size_t OFF_BSUM  = 1572864;   // NB_SCAN int
static const size_t OFF_BSUMX = 1576960;   // NB_SCAN int
static const size_t OFF_CNT   = 1581056;   // NN int histogram
static const size_t OFF_PT    = 2097152;   // NE int2 {edge, tgt} sorted (8 MB)
static const size_t OFF_EVALS = 10485760;  // NE f32 (sorted order, 4 MB)
static const size_t OFF_ATTNS = 14485760;  // NE f32 attn sorted (4 MB)
static const size_t OFF_EAS   = 18485760;  // NE * 5 uint (bf16x10 packed, 20 MB)
static const size_t OFF_SNODE = 38485760;  // NN*128 bf16 (25.6 MB) -> total ~64.1 MB

__device__ inline unsigned short f2bf(float f) {
    const unsigned int u = __float_as_uint(f);
    return (unsigned short)((u + 0x7fffu + ((u >> 16) & 1u)) >> 16);  // RNE
}

__device__ inline unsigned int cvtpk(float lo, float hi) {
    unsigned int r;
    asm("v_cvt_pk_bf16_f32 %0, %1, %2" : "=v"(r) : "v"(lo), "v"(hi));
    return r;  // [15:0]=bf16(lo), [31:16]=bf16(hi), RNE
}

__device__ inline float lk(float v) {  // leaky_relu 0.01
    return fmaxf(v, 0.f) + 0.01f * fminf(v, 0.f);
}

union BU { bf16x8 v; uint4 u; };

// ---------------------------------------------------------------------------
// prep: w1k = bf16(Wk) K-padded to 32; wvk = bf16(Wv) K-padded to 32;
// w1bp = W1b slot-permuted bf16; mtb[i][l] = bf16((W1a@Wq)[i][l]).
// ---------------------------------------------------------------------------
__global__ __launch_bounds__(128) void prep_kernel(
    const float* __restrict__ W1, const float* __restrict__ Wq,
    const float* __restrict__ Wk, const float* __restrict__ Wv,
    unsigned short* __restrict__ w1k, unsigned short* __restrict__ wvk,
    unsigned short* __restrict__ w1bp, unsigned short* __restrict__ mtb)
{
    const int l = blockIdx.x;   // 0..127
    const int i = threadIdx.x;  // 0..127
    float acc = 0.f;
#pragma unroll 8
    for (int j = 0; j < 128; ++j)
        acc = fmaf(W1[i * 256 + j], Wq[j * 128 + l], acc);
    mtb[i * 128 + l] = f2bf(acc);
    if (i < 32) {
        w1k[l * 32 + i] = (i < 10) ? f2bf(Wk[l * 10 + i]) : (unsigned short)0;
        wvk[l * 32 + i] = (i < 10) ? f2bf(Wv[l * 10 + i]) : (unsigned short)0;
    }
    const int m = l;
    const int j = (m & ~31) + 16 * ((m >> 2) & 1) + 4 * ((m >> 3) & 3) + (m & 3);
    w1bp[i * 128 + m] = f2bf(W1[i * 256 + 128 + j]);
}

// ---------------------------------------------------------------------------
// node scores via MFMA: s_node[n][i] = bf16( x[n]@M^T + b1 )
// ---------------------------------------------------------------------------
__global__ __launch_bounds__(256) void node_score_kernel(
    const float* __restrict__ x, const unsigned short* __restrict__ mtb_g,
    const float* __restrict__ b1, unsigned short* __restrict__ s_node)
{
    __shared__ __align__(16) unsigned short mt_s[128 * 136];
    const int t = threadIdx.x;
    for (int idx = t; idx < 2048; idx += 256) {
        const uint4 v = ((const uint4*)mtb_g)[idx];
        const int row = idx >> 4, q = idx & 15;
        *(uint4*)&mt_s[row * 136 + q * 8] = v;
    }
    __syncthreads();

    const int lane = t & 63;
    const int wave = t >> 6;
    const int h    = lane >> 4;
    const int e15  = lane & 15;
    const int node = blockIdx.x * 64 + wave * 16 + e15;
    const int nc   = min(node, NN - 1);
    const int lds_base = e15 * 136 + h * 8;

    const f32x4 z4 = {0.f, 0.f, 0.f, 0.f};
    f32x4 acc[8];
#pragma unroll
    for (int g = 0; g < 8; ++g) acc[g] = z4;

#pragma unroll
    for (int s = 0; s < 4; ++s) {
        const float4 xa = *(const float4*)&x[(size_t)nc * 128 + s * 32 + h * 8];
        const float4 xb = *(const float4*)&x[(size_t)nc * 128 + s * 32 + h * 8 + 4];
        BU bx;
        bx.u.x = cvtpk(xa.x, xa.y);
        bx.u.y = cvtpk(xa.z, xa.w);
        bx.u.z = cvtpk(xb.x, xb.y);
        bx.u.w = cvtpk(xb.z, xb.w);
#pragma unroll
        for (int g = 0; g < 8; ++g) {
            const bf16x8 a = *(const bf16x8*)&mt_s[lds_base + g * (16 * 136) + s * 32];
            acc[g] = __builtin_amdgcn_mfma_f32_16x16x32_bf16(a, bx.v, acc[g], 0, 0, 0);
        }
    }

    if (node < NN) {
#pragma unroll
        for (int g = 0; g < 8; ++g) {
            const float4 bb = *(const float4*)&b1[g * 16 + h * 4];
            uint2 o2;
            o2.x = cvtpk(acc[g][0] + bb.x, acc[g][1] + bb.y);
            o2.y = cvtpk(acc[g][2] + bb.z, acc[g][3] + bb.w);
            *(uint2*)&s_node[(size_t)node * 128 + g * 16 + h * 4] = o2;
        }
    }
}

// ---------------------------------------------------------------------------
// CSR build: histogram -> block scan -> fill {edge,tgt} pairs in sorted order
// ---------------------------------------------------------------------------
__global__ __launch_bounds__(256) void hist_kernel(
    const int* __restrict__ tgt, int* __restrict__ cnt)
{
    const int e = blockIdx.x * 256 + threadIdx.x;
    if (e < NE) atomicAdd(&cnt[tgt[e]], 1);
}

__global__ __launch_bounds__(256) void scan1_kernel(
    const int* __restrict__ cnt, int* __restrict__ part, int* __restrict__ bsum)
{
    __shared__ int s[256];
    const int t = threadIdx.x;
    const int idx = blockIdx.x * 256 + t;
    const int v = (idx < NN) ? cnt[idx] : 0;
    s[t] = v;
    __syncthreads();
    for (int off = 1; off < 256; off <<= 1) {
        const int u = (t >= off) ? s[t - off] : 0;
        __syncthreads();
        s[t] += u;
        __syncthreads();
    }
    part[idx] = s[t] - v;  // exclusive
    if (t == 255) bsum[blockIdx.x] = s[255];
}

__global__ __launch_bounds__(512) void scan2_kernel(
    const int* __restrict__ bsum, int* __restrict__ bsumx)
{
    __shared__ int s[512];
    const int t = threadIdx.x;
    const int v = (t < NB_SCAN) ? bsum[t] : 0;
    s[t] = v;
    __syncthreads();
    for (int off = 1; off < 512; off <<= 1) {
        const int u = (t >= off) ? s[t - off] : 0;
        __syncthreads();
        s[t] += u;
        __syncthreads();
    }
    if (t < NB_SCAN) bsumx[t] = s[t] - v;  // exclusive
}

__global__ __launch_bounds__(256) void scan3_kernel(
    const int* __restrict__ part, const int* __restrict__ bsumx,
    int* __restrict__ rowptr, int* __restrict__ cursor)
{
    const int idx = blockIdx.x * 256 + threadIdx.x;
    if (idx < NN) {
        const int rp = part[idx] + bsumx[idx >> 8];
        rowptr[idx] = rp;
        cursor[idx] = rp;
    }
    if (idx == 0) rowptr[NN] = NE;
}

__global__ __launch_bounds__(256) void fill_kernel(
    const int* __restrict__ tgt, int* __restrict__ cursor, int2* __restrict__ pt)
{
    const int e = blockIdx.x * 256 + threadIdx.x;
    if (e < NE) {
        const int tg = tgt[e];
        const int p  = atomicAdd(&cursor[tg], 1);
        pt[p] = make_int2(e, tg);
    }
}

// ---------------------------------------------------------------------------
// edge scores via MFMA, CSR-sorted, 2-deep software pipeline (R8, unchanged).
// ---------------------------------------------------------------------------
__global__ __launch_bounds__(256) void edge_kernel(
    const float* __restrict__ edge_attr, const int2* __restrict__ pt,
    const unsigned short* __restrict__ w1k_g, const unsigned short* __restrict__ w1bp_g,
    const float* __restrict__ W2, const float* __restrict__ b2,
    const unsigned short* __restrict__ s_node,
    float* __restrict__ e_vals, unsigned int* __restrict__ eas)
{
    __shared__ __align__(16) unsigned short w1b_s[128 * 136];

    const int t = threadIdx.x;
    for (int idx = t; idx < 2048; idx += 256) {
        const uint4 v = ((const uint4*)w1bp_g)[idx];
        const int row = idx >> 4, q = idx & 15;
        *(uint4*)&w1b_s[row * 136 + q * 8] = v;
    }

    const int lane = t & 63;
    const int wave = t >> 6;
    const int h    = lane >> 4;
    const int e15  = lane & 15;

    bf16x8 a1[8];
#pragma unroll
    for (int f = 0; f < 8; ++f)
        a1[f] = *(const bf16x8*)&w1k_g[(f * 16 + e15) * 32 + h * 8];
    const float b2v = b2[0];

    __syncthreads();

    const int lds_base = e15 * 136 + h * 8;
    const int cstep    = gridDim.x * 64;

    int c = blockIdx.x * 64 + wave * 16 + e15;  // sorted edge index

    int2 ptc = pt[min(c, NE - 1)];
    int2 ptn = pt[min(c + cstep, NE - 1)];

    uint2 sn[8];
#pragma unroll
    for (int g = 0; g < 8; ++g)
        sn[g] = *(const uint2*)&s_node[(size_t)ptc.y * 128 + g * 16 + h * 4];

    float ea0 = 0.f, ea1 = 0.f, ea2 = 0.f, ea3 = 0.f, ea4 = 0.f;
    float ea5 = 0.f, ea6 = 0.f, ea7 = 0.f, ea8 = 0.f, ea9 = 0.f;
    {
        const float* pa = edge_attr + (size_t)ptc.x * 10;
        if (h == 0) {
            const float2 u0 = *(const float2*)(pa + 0);
            const float2 u1 = *(const float2*)(pa + 2);
            const float2 u2 = *(const float2*)(pa + 4);
            const float2 u3 = *(const float2*)(pa + 6);
            ea0 = u0.x; ea1 = u0.y; ea2 = u1.x; ea3 = u1.y;
            ea4 = u2.x; ea5 = u2.y; ea6 = u3.x; ea7 = u3.y;
        } else if (h == 1) {
            const float2 u4 = *(const float2*)(pa + 8);
            ea8 = u4.x; ea9 = u4.y;
        }
    }

    for (int tile = blockIdx.x; tile < NTILES; tile += gridDim.x, c += cstep) {
        const int2 ptn2 = pt[min(c + 2 * cstep, NE - 1)];
        uint2 sn_n[8];
#pragma unroll
        for (int g = 0; g < 8; ++g)
            sn_n[g] = *(const uint2*)&s_node[(size_t)ptn.y * 128 + g * 16 + h * 4];
        float en0 = 0.f, en1 = 0.f, en2 = 0.f, en3 = 0.f, en4 = 0.f;
        float en5 = 0.f, en6 = 0.f, en7 = 0.f, en8 = 0.f, en9 = 0.f;
        {
            const float* pa = edge_attr + (size_t)ptn.x * 10;
            if (h == 0) {
                const float2 u0 = *(const float2*)(pa + 0);
                const float2 u1 = *(const float2*)(pa + 2);
                const float2 u2 = *(const float2*)(pa + 4);
                const float2 u3 = *(const float2*)(pa + 6);
                en0 = u0.x; en1 = u0.y; en2 = u1.x; en3 = u1.y;
                en4 = u2.x; en5 = u2.y; en6 = u3.x; en7 = u3.y;
            } else if (h == 1) {
                const float2 u4 = *(const float2*)(pa + 8);
                en8 = u4.x; en9 = u4.y;
            }
        }

        bf16x8 b1 = (bf16x8){0, 0, 0, 0, 0, 0, 0, 0};
        {
            unsigned int* po = eas + (size_t)c * 5;
            if (h == 0) {
                BU bu;
                bu.u.x = cvtpk(ea0, ea1);
                bu.u.y = cvtpk(ea2, ea3);
                bu.u.z = cvtpk(ea4, ea5);
                bu.u.w = cvtpk(ea6, ea7);
                b1 = bu.v;
                po[0] = bu.u.x; po[1] = bu.u.y; po[2] = bu.u.z; po[3] = bu.u.w;
            } else if (h == 1) {
                BU bu;
                bu.u.x = cvtpk(ea8, ea9);
                bu.u.y = 0; bu.u.z = 0; bu.u.w = 0;
                b1 = bu.v;
                po[4] = bu.u.x;
            }
        }

        const f32x4 z4 = {0.f, 0.f, 0.f, 0.f};
        f32x4 acc1[8];
#pragma unroll
        for (int f = 0; f < 8; ++f)
            acc1[f] = __builtin_amdgcn_mfma_f32_16x16x32_bf16(a1[f], b1, z4, 0, 0, 0);

        bf16x8 pb[4];
#pragma unroll
        for (int s = 0; s < 4; ++s) {
            BU bu;
            bu.u.x = cvtpk(lk(acc1[2 * s][0]), lk(acc1[2 * s][1]));
            bu.u.y = cvtpk(lk(acc1[2 * s][2]), lk(acc1[2 * s][3]));
            bu.u.z = cvtpk(lk(acc1[2 * s + 1][0]), lk(acc1[2 * s + 1][1]));
            bu.u.w = cvtpk(lk(acc1[2 * s + 1][2]), lk(acc1[2 * s + 1][3]));
            pb[s] = bu.v;
        }

        float p = 0.f;
#pragma unroll
        for (int g2 = 0; g2 < 4; ++g2) {
            const int gA = 2 * g2, gB = 2 * g2 + 1;
            f32x4 accA = z4, accB = z4;
#pragma unroll
            for (int s = 0; s < 4; ++s) {
                const bf16x8 a2A = *(const bf16x8*)&w1b_s[lds_base + gA * (16 * 136) + s * 32];
                const bf16x8 a2B = *(const bf16x8*)&w1b_s[lds_base + gB * (16 * 136) + s * 32];
                accA = __builtin_amdgcn_mfma_f32_16x16x32_bf16(a2A, pb[s], accA, 0, 0, 0);
                accB = __builtin_amdgcn_mfma_f32_16x16x32_bf16(a2B, pb[s], accB, 0, 0, 0);
            }
            const float4 w2A = *(const float4*)&W2[gA * 16 + h * 4];
            const float4 w2B = *(const float4*)&W2[gB * 16 + h * 4];
            const uint2 svA = sn[gA], svB = sn[gB];
            p = fmaf(fmaxf(accA[0] + __uint_as_float(svA.x << 16), 0.f), w2A.x, p);
            p = fmaf(fmaxf(accA[1] + __uint_as_float(svA.x & 0xffff0000u), 0.f), w2A.y, p);
            p = fmaf(fmaxf(accA[2] + __uint_as_float(svA.y << 16), 0.f), w2A.z, p);
            p = fmaf(fmaxf(accA[3] + __uint_as_float(svA.y & 0xffff0000u), 0.f), w2A.w, p);
            p = fmaf(fmaxf(accB[0] + __uint_as_float(svB.x << 16), 0.f), w2B.x, p);
            p = fmaf(fmaxf(accB[1] + __uint_as_float(svB.x & 0xffff0000u), 0.f), w2B.y, p);
            p = fmaf(fmaxf(accB[2] + __uint_as_float(svB.y << 16), 0.f), w2B.z, p);
            p = fmaf(fmaxf(accB[3] + __uint_as_float(svB.y & 0xffff0000u), 0.f), w2B.w, p);
        }
        p += __shfl_xor(p, 16);
        p += __shfl_xor(p, 32);
        if (lane < 16)
            e_vals[c - e15 + lane] = __expf(p + b2v);

        ptc = ptn; ptn = ptn2;
#pragma unroll
        for (int g = 0; g < 8; ++g) sn[g] = sn_n[g];
        ea0 = en0; ea1 = en1; ea2 = en2; ea3 = en3; ea4 = en4;
        ea5 = en5; ea6 = en6; ea7 = en7; ea8 = en8; ea9 = en9;
    }
}

// ---------------------------------------------------------------------------
// denom: per-node run-sum of e_vals (coalesced-ish) -> inv_denom.
// Also zeroes out-rows whose run crosses a 64-edge tile boundary (vscatter
// accumulates those with atomics onto zero).
// ---------------------------------------------------------------------------
__global__ __launch_bounds__(256) void denom_kernel(
    const int* __restrict__ rowptr, const float* __restrict__ e_vals,
    float* __restrict__ inv_denom, float* __restrict__ out)
{
    const int n = blockIdx.x * 256 + threadIdx.x;
    if (n >= NN) return;
    const int rs = rowptr[n], re = rowptr[n + 1];
    float s = 0.f;
    for (int c = rs; c < re; ++c) s += e_vals[c];
    inv_denom[n] = 1.f / (s + 1e-16f);
    if (re > rs && (rs >> 6) != ((re - 1) >> 6)) {
        const float4 z = make_float4(0.f, 0.f, 0.f, 0.f);
        float4* po = (float4*)&out[(size_t)n * 128];
#pragma unroll 8
        for (int q = 0; q < 32; ++q) po[q] = z;
    }
}

// ---------------------------------------------------------------------------
// attn: attn_sorted[c] = e_vals[c]*inv_denom[tgt]; scatter attn_out[orig e].
// ---------------------------------------------------------------------------
__global__ __launch_bounds__(256) void attn_kernel(
    const int2* __restrict__ pt, const float* __restrict__ e_vals,
    const float* __restrict__ inv_denom,
    float* __restrict__ attn_s, float* __restrict__ attn_out)
{
    const int c = blockIdx.x * 256 + threadIdx.x;
    if (c >= NE) return;
    const int2 p = pt[c];
    const float a = e_vals[c] * inv_denom[p.y];
    attn_s[c] = a;
    attn_out[p.x] = a;
}

// ---------------------------------------------------------------------------
// vscatter: one block per 64 sorted edges. Phase 1 (per wave, 16 edges):
// v[i][e] = Wv@ea via 8 MFMA (A=wvk rows, B=eas frags), +bv, leaky, *attn,
// dump to LDS [64][132] (padded: 2-way banks only). Phase 2: rowptr-guided
// segment sum over LDS columns; complete nodes -> plain float2 store/lane;
// boundary nodes -> atomicAdd partials (rows pre-zeroed by denom_kernel).
// ---------------------------------------------------------------------------
__global__ __launch_bounds__(256) void vscatter_kernel(
    const int* __restrict__ rowptr, const int2* __restrict__ pt,
    const unsigned int* __restrict__ eas, const float* __restrict__ attn_s,
    const unsigned short* __restrict__ wvk_g, const float* __restrict__ bv,
    float* __restrict__ out)
{
    __shared__ __align__(16) float w_lds[64 * 132];  // 33792 B

    const int t    = threadIdx.x;
    const int lane = t & 63;
    const int wv   = t >> 6;
    const int h    = lane >> 4;
    const int e15  = lane & 15;
    const int base = blockIdx.x * 64;
    const int c    = base + wv * 16 + e15;
    const int el   = wv * 16 + e15;  // local edge row in LDS

    // A-frags: Wv rows (K padded to 32)
    bf16x8 av[8];
#pragma unroll
    for (int g = 0; g < 8; ++g)
        av[g] = *(const bf16x8*)&wvk_g[(g * 16 + e15) * 32 + h * 8];

    // B-frag from eas (bf16-packed channels)
    bf16x8 be = (bf16x8){0, 0, 0, 0, 0, 0, 0, 0};
    {
        const unsigned int* pe = eas + (size_t)c * 5;
        if (h == 0) {
            BU bu;
            bu.u.x = pe[0]; bu.u.y = pe[1]; bu.u.z = pe[2]; bu.u.w = pe[3];
            be = bu.v;
        } else if (h == 1) {
            BU bu;
            bu.u.x = pe[4]; bu.u.y = 0; bu.u.z = 0; bu.u.w = 0;
            be = bu.v;
        }
    }
    const float at = attn_s[c];

    const f32x4 z4 = {0.f, 0.f, 0.f, 0.f};
#pragma unroll
    for (int g = 0; g < 8; ++g) {
        const f32x4 acc = __builtin_amdgcn_mfma_f32_16x16x32_bf16(av[g], be, z4, 0, 0, 0);
        const float4 bb = *(const float4*)&bv[g * 16 + h * 4];
        float4 w;
        w.x = at * lk(acc[0] + bb.x);
        w.y = at * lk(acc[1] + bb.y);
        w.z = at * lk(acc[2] + bb.z);
        w.w = at * lk(acc[3] + bb.w);
        *(float4*)&w_lds[el * 132 + g * 16 + h * 4] = w;
    }
    __syncthreads();

    // phase 2: segment sums. Each wave handles nodes round-robin; lane owns
    // dims (2*lane, 2*lane+1).
    const int n_lo = (blockIdx.x == 0) ? 0 : pt[base].y;
    const int n_hi = (blockIdx.x == (int)gridDim.x - 1) ? (NN - 1) : pt[base + 64].y;

    for (int nd = n_lo + wv; nd <= n_hi; nd += 4) {
        const int rs = rowptr[nd], re = rowptr[nd + 1];
        const int lo = max(rs, base), hi = min(re, base + 64);
        float sx = 0.f, sy = 0.f;
        for (int cc = lo; cc < hi; ++cc) {
            const float2 v = *(const float2*)&w_lds[(cc - base) * 132 + lane * 2];
            sx += v.x; sy += v.y;
        }
        float* po = &out[(size_t)nd * 128 + lane * 2];
        if (rs >= base && re <= base + 64) {
            *(float2*)po = make_float2(sx, sy);   // complete node
        } else {
            atomicAdd(po, sx);                     // partial (row pre-zeroed)
            atomicAdd(po + 1, sy);
        }
    }
}

extern "C" void kernel_launch(void* const* d_in, const int* in_sizes, int n_in,
                              void* d_out, int out_size, void* d_ws, size_t ws_size,
                              hipStream_t stream)
{
    const float* x         = (const float*)d_in[0];
    const int*   eidx      = (const int*)d_in[1];
    const float* edge_attr = (const float*)d_in[2];
    const float* Wq        = (const float*)d_in[3];
    const float* Wk        = (const float*)d_in[4];
    const float* Wv        = (const float*)d_in[5];
    const float* bv        = (const float*)d_in[6];
    const float* W1        = (const float*)d_in[7];
    const float* b1        = (const float*)d_in[8];
    const float* W2        = (const float*)d_in[9];
    const float* b2        = (const float*)d_in[10];
    const int*   tgt       = eidx + NE;  // edge_index[1]

    char* ws = (char*)d_ws;
    unsigned short* w1k    = (unsigned short*)(ws + OFF_W1K);
    unsigned short* wvk    = (unsigned short*)(ws + OFF_WVK);
    unsigned short* w1bp   = (unsigned short*)(ws + OFF_W1BP);
    unsigned short* mtb    = (unsigned short*)(ws + OFF_MTB);
    int*            rowptr = (int*)(ws + OFF_RP);
    int*            cursor = (int*)(ws + OFF_CUR);
    float*          invd   = (float*)(ws + OFF_CUR);  // alias: cursor dead after fill
    int*            part   = (int*)(ws + OFF_PART);
    int*            bsum   = (int*)(ws + OFF_BSUM);
    int*            bsumx  = (int*)(ws + OFF_BSUMX);
    int*            cnt    = (int*)(ws + OFF_CNT);
    int2*           pt     = (int2*)(ws + OFF_PT);
    float*          e_vals = (float*)(ws + OFF_EVALS);
    float*          attn_s = (float*)(ws + OFF_ATTNS);
    unsigned int*   eas    = (unsigned int*)(ws + OFF_EAS);
    unsigned short* s_node = (unsigned short*)(ws + OFF_SNODE);

    float* out      = (float*)d_out;
    float* attn_out = out + (size_t)NN * 128;

    hipMemsetAsync(cnt, 0, (size_t)NN * sizeof(int), stream);

    prep_kernel<<<128, 128, 0, stream>>>(W1, Wq, Wk, Wv, w1k, wvk, w1bp, mtb);
    node_score_kernel<<<(NN + 63) / 64, 256, 0, stream>>>(x, mtb, b1, s_node);
    hist_kernel<<<(NE + 255) / 256, 256, 0, stream>>>(tgt, cnt);
    scan1_kernel<<<NB_SCAN, 256, 0, stream>>>(cnt, part, bsum);
    scan2_kernel<<<1, 512, 0, stream>>>(bsum, bsumx);
    scan3_kernel<<<NB_SCAN, 256, 0, stream>>>(part, bsumx, rowptr, cursor);
    fill_kernel<<<(NE + 255) / 256, 256, 0, stream>>>(tgt, cursor, pt);
    edge_kernel<<<768, 256, 0, stream>>>(edge_attr, pt, w1k, w1bp, W2, b2,
                                         s_node, e_vals, eas);
    denom_kernel<<<(NN + 255) / 256, 256, 0, stream>>>(rowptr, e_vals, invd, out);
    attn_kernel<<<(NE + 255) / 256, 256, 0, stream>>>(pt, e_vals, invd,
                                                      attn_s, attn_out);
    vscatter_kernel<<<NTILES, 256, 0, stream>>>(rowptr, pt, eas, attn_s,
                                                wvk, bv, out);
}

// Round 10
// 320.686 us; speedup vs baseline: 2.1382x; 1.0260x over previous
//
#include <hip/hip_runtime.h>
#include <stdint.h>

#define NN 100000
#define NE 1000000
#define NTILES (NE / 64)
#define NB_SCAN 391  // ceil(NN/256)

typedef __attribute__((ext_vector_type(8))) short bf16x8;
typedef __attribute__((ext_vector_type(4))) float f32x4;

// ws layout (bytes)
static const size_t OFF_W1K   = 0;         // 128*32 bf16 (8 KB)
static const size_t OFF_WVK   = 8192;      // 128*32 bf16 (8 KB): Wv K-padded
static const size_t OFF_W1BP  = 16384;     // 128*128 bf16 (32 KB), MFMA read-order
static const size_t OFF_MTB   = 49152;     // 128*128 bf16 (32 KB), MFMA read-order
static const size_t OFF_RP    = 81920;     // (NN+1) int rowptr
static const size_t OFF_CUR   = 524288;    // NN int cursor; later aliased as inv_denom
static const size_t OFF_PART  = 1048576;   // NB_SCAN*256 int
static const size_t OFF_BSUM  = 1572864;   // NB_SCAN int
static const size_t OFF_BSUMX = 1576960;   // NB_SCAN int
static const size_t OFF_CNT   = 1581056;   // NN int histogram
static const size_t OFF_PT    = 2097152;   // NE int2 {edge, tgt} sorted (8 MB)
static const size_t OFF_EVALS = 10485760;  // NE f32 (sorted order, 4 MB)
static const size_t OFF_EAS   = 14485760;  // NE * 5 uint (bf16x10 packed, 20 MB)
static const size_t OFF_SNODE = 34485760;  // NN*128 bf16 (25.6 MB)

__device__ inline unsigned short f2bf(float f) {
    const unsigned int u = __float_as_uint(f);
    return (unsigned short)((u + 0x7fffu + ((u >> 16) & 1u)) >> 16);  // RNE
}

__device__ inline unsigned int cvtpk(float lo, float hi) {
    unsigned int r;
    asm("v_cvt_pk_bf16_f32 %0, %1, %2" : "=v"(r) : "v"(lo), "v"(hi));
    return r;
}

__device__ inline float lk(float v) {  // leaky_relu 0.01
    return fmaxf(v, 0.f) + 0.01f * fminf(v, 0.f);
}

// MFMA read-order linear index for a [128 rows i][128 cols m] operand:
// L = (g*4+s)*512 + (e15*4+h)*8 + jj  with i = g*16+e15, m = s*32+h*8+jj.
// A wave's read at fixed (g,s) is then 64 contiguous 16B chunks -> 0 conflicts.
__device__ __host__ inline int mfma_order(int i, int m) {
    const int g = i >> 4, e15 = i & 15;
    const int s = m >> 5, h = (m >> 3) & 3, jj = m & 7;
    return (g * 4 + s) * 512 + (e15 * 4 + h) * 8 + jj;
}

union BU { bf16x8 v; uint4 u; };

// ---------------------------------------------------------------------------
// prep: w1k/wvk = bf16(Wk/Wv) K-padded to 32; w1bp = W1b slot-permuted bf16
// in MFMA read-order; mtb = (W1a@Wq) bf16 in MFMA read-order.
// ---------------------------------------------------------------------------
__global__ __launch_bounds__(128) void prep_kernel(
    const float* __restrict__ W1, const float* __restrict__ Wq,
    const float* __restrict__ Wk, const float* __restrict__ Wv,
    unsigned short* __restrict__ w1k, unsigned short* __restrict__ wvk,
    unsigned short* __restrict__ w1bp, unsigned short* __restrict__ mtb)
{
    const int l = blockIdx.x;   // 0..127 (the m index)
    const int i = threadIdx.x;  // 0..127
    float acc = 0.f;
#pragma unroll 8
    for (int j = 0; j < 128; ++j)
        acc = fmaf(W1[i * 256 + j], Wq[j * 128 + l], acc);
    mtb[mfma_order(i, l)] = f2bf(acc);
    if (i < 32) {
        w1k[l * 32 + i] = (i < 10) ? f2bf(Wk[l * 10 + i]) : (unsigned short)0;
        wvk[l * 32 + i] = (i < 10) ? f2bf(Wv[l * 10 + i]) : (unsigned short)0;
    }
    const int m = l;
    const int j = (m & ~31) + 16 * ((m >> 2) & 1) + 4 * ((m >> 3) & 3) + (m & 3);
    w1bp[mfma_order(i, m)] = f2bf(W1[i * 256 + 128 + j]);
}

// ---------------------------------------------------------------------------
// node scores via MFMA: s_node[n][i] = bf16( x[n]@M^T + b1 ); C-init = b1.
// ---------------------------------------------------------------------------
__global__ __launch_bounds__(256) void node_score_kernel(
    const float* __restrict__ x, const unsigned short* __restrict__ mtb_g,
    const float* __restrict__ b1, unsigned short* __restrict__ s_node)
{
    __shared__ __align__(16) unsigned short mt_s[128 * 128];
    const int t = threadIdx.x;
    for (int idx = t; idx < 2048; idx += 256)
        *(uint4*)&mt_s[idx * 8] = ((const uint4*)mtb_g)[idx];
    __syncthreads();

    const int lane = t & 63;
    const int wave = t >> 6;
    const int h    = lane >> 4;
    const int e15  = lane & 15;
    const int node = blockIdx.x * 64 + wave * 16 + e15;
    const int nc   = min(node, NN - 1);
    const int slot8 = (e15 * 4 + h) * 8;

    f32x4 acc[8];
#pragma unroll
    for (int g = 0; g < 8; ++g) {
        const float4 bb = *(const float4*)&b1[g * 16 + h * 4];
        acc[g][0] = bb.x; acc[g][1] = bb.y; acc[g][2] = bb.z; acc[g][3] = bb.w;
    }

#pragma unroll
    for (int s = 0; s < 4; ++s) {
        const float4 xa = *(const float4*)&x[(size_t)nc * 128 + s * 32 + h * 8];
        const float4 xb = *(const float4*)&x[(size_t)nc * 128 + s * 32 + h * 8 + 4];
        BU bx;
        bx.u.x = cvtpk(xa.x, xa.y);
        bx.u.y = cvtpk(xa.z, xa.w);
        bx.u.z = cvtpk(xb.x, xb.y);
        bx.u.w = cvtpk(xb.z, xb.w);
#pragma unroll
        for (int g = 0; g < 8; ++g) {
            const bf16x8 a = *(const bf16x8*)&mt_s[(g * 4 + s) * 512 + slot8];
            acc[g] = __builtin_amdgcn_mfma_f32_16x16x32_bf16(a, bx.v, acc[g], 0, 0, 0);
        }
    }

    if (node < NN) {
#pragma unroll
        for (int g = 0; g < 8; ++g) {
            uint2 o2;
            o2.x = cvtpk(acc[g][0], acc[g][1]);
            o2.y = cvtpk(acc[g][2], acc[g][3]);
            *(uint2*)&s_node[(size_t)node * 128 + g * 16 + h * 4] = o2;
        }
    }
}

// ---------------------------------------------------------------------------
// CSR build: histogram -> block scan -> fill {edge,tgt} pairs in sorted order
// ---------------------------------------------------------------------------
__global__ __launch_bounds__(256) void hist_kernel(
    const int* __restrict__ tgt, int* __restrict__ cnt)
{
    const int e = blockIdx.x * 256 + threadIdx.x;
    if (e < NE) atomicAdd(&cnt[tgt[e]], 1);
}

__global__ __launch_bounds__(256) void scan1_kernel(
    const int* __restrict__ cnt, int* __restrict__ part, int* __restrict__ bsum)
{
    __shared__ int s[256];
    const int t = threadIdx.x;
    const int idx = blockIdx.x * 256 + t;
    const int v = (idx < NN) ? cnt[idx] : 0;
    s[t] = v;
    __syncthreads();
    for (int off = 1; off < 256; off <<= 1) {
        const int u = (t >= off) ? s[t - off] : 0;
        __syncthreads();
        s[t] += u;
        __syncthreads();
    }
    part[idx] = s[t] - v;  // exclusive
    if (t == 255) bsum[blockIdx.x] = s[255];
}

__global__ __launch_bounds__(512) void scan2_kernel(
    const int* __restrict__ bsum, int* __restrict__ bsumx)
{
    __shared__ int s[512];
    const int t = threadIdx.x;
    const int v = (t < NB_SCAN) ? bsum[t] : 0;
    s[t] = v;
    __syncthreads();
    for (int off = 1; off < 512; off <<= 1) {
        const int u = (t >= off) ? s[t - off] : 0;
        __syncthreads();
        s[t] += u;
        __syncthreads();
    }
    if (t < NB_SCAN) bsumx[t] = s[t] - v;  // exclusive
}

__global__ __launch_bounds__(256) void scan3_kernel(
    const int* __restrict__ part, const int* __restrict__ bsumx,
    int* __restrict__ rowptr, int* __restrict__ cursor)
{
    const int idx = blockIdx.x * 256 + threadIdx.x;
    if (idx < NN) {
        const int rp = part[idx] + bsumx[idx >> 8];
        rowptr[idx] = rp;
        cursor[idx] = rp;
    }
    if (idx == 0) rowptr[NN] = NE;
}

__global__ __launch_bounds__(256) void fill_kernel(
    const int* __restrict__ tgt, int* __restrict__ cursor, int2* __restrict__ pt)
{
    const int e = blockIdx.x * 256 + threadIdx.x;
    if (e < NE) {
        const int tg = tgt[e];
        const int p  = atomicAdd(&cursor[tg], 1);
        pt[p] = make_int2(e, tg);
    }
}

// ---------------------------------------------------------------------------
// edge scores via MFMA, CSR-sorted, 2-deep pipeline. w1b_s in MFMA read-order
// (contiguous 1KB wave reads -> 0 bank conflicts). s_node enters phase-2 as
// the MFMA C-initializer (epilogue adds removed).
// ---------------------------------------------------------------------------
__global__ __launch_bounds__(256) void edge_kernel(
    const float* __restrict__ edge_attr, const int2* __restrict__ pt,
    const unsigned short* __restrict__ w1k_g, const unsigned short* __restrict__ w1bp_g,
    const float* __restrict__ W2, const float* __restrict__ b2,
    const unsigned short* __restrict__ s_node,
    float* __restrict__ e_vals, unsigned int* __restrict__ eas)
{
    __shared__ __align__(16) unsigned short w1b_s[128 * 128];  // 32 KB, read-order

    const int t = threadIdx.x;
    for (int idx = t; idx < 2048; idx += 256)
        *(uint4*)&w1b_s[idx * 8] = ((const uint4*)w1bp_g)[idx];

    const int lane = t & 63;
    const int wave = t >> 6;
    const int h    = lane >> 4;
    const int e15  = lane & 15;

    bf16x8 a1[8];
#pragma unroll
    for (int f = 0; f < 8; ++f)
        a1[f] = *(const bf16x8*)&w1k_g[(f * 16 + e15) * 32 + h * 8];
    const float b2v = b2[0];

    __syncthreads();

    const int slot8 = (e15 * 4 + h) * 8;
    const int cstep = gridDim.x * 64;

    int c = blockIdx.x * 64 + wave * 16 + e15;  // sorted edge index

    int2 ptc = pt[min(c, NE - 1)];
    int2 ptn = pt[min(c + cstep, NE - 1)];

    uint2 sn[8];
#pragma unroll
    for (int g = 0; g < 8; ++g)
        sn[g] = *(const uint2*)&s_node[(size_t)ptc.y * 128 + g * 16 + h * 4];

    float ea0 = 0.f, ea1 = 0.f, ea2 = 0.f, ea3 = 0.f, ea4 = 0.f;
    float ea5 = 0.f, ea6 = 0.f, ea7 = 0.f, ea8 = 0.f, ea9 = 0.f;
    {
        const float* pa = edge_attr + (size_t)ptc.x * 10;
        if (h == 0) {
            const float2 u0 = *(const float2*)(pa + 0);
            const float2 u1 = *(const float2*)(pa + 2);
            const float2 u2 = *(const float2*)(pa + 4);
            const float2 u3 = *(const float2*)(pa + 6);
            ea0 = u0.x; ea1 = u0.y; ea2 = u1.x; ea3 = u1.y;
            ea4 = u2.x; ea5 = u2.y; ea6 = u3.x; ea7 = u3.y;
        } else if (h == 1) {
            const float2 u4 = *(const float2*)(pa + 8);
            ea8 = u4.x; ea9 = u4.y;
        }
    }

    for (int tile = blockIdx.x; tile < NTILES; tile += gridDim.x, c += cstep) {
        const int2 ptn2 = pt[min(c + 2 * cstep, NE - 1)];
        uint2 sn_n[8];
#pragma unroll
        for (int g = 0; g < 8; ++g)
            sn_n[g] = *(const uint2*)&s_node[(size_t)ptn.y * 128 + g * 16 + h * 4];
        float en0 = 0.f, en1 = 0.f, en2 = 0.f, en3 = 0.f, en4 = 0.f;
        float en5 = 0.f, en6 = 0.f, en7 = 0.f, en8 = 0.f, en9 = 0.f;
        {
            const float* pa = edge_attr + (size_t)ptn.x * 10;
            if (h == 0) {
                const float2 u0 = *(const float2*)(pa + 0);
                const float2 u1 = *(const float2*)(pa + 2);
                const float2 u2 = *(const float2*)(pa + 4);
                const float2 u3 = *(const float2*)(pa + 6);
                en0 = u0.x; en1 = u0.y; en2 = u1.x; en3 = u1.y;
                en4 = u2.x; en5 = u2.y; en6 = u3.x; en7 = u3.y;
            } else if (h == 1) {
                const float2 u4 = *(const float2*)(pa + 8);
                en8 = u4.x; en9 = u4.y;
            }
        }

        bf16x8 b1 = (bf16x8){0, 0, 0, 0, 0, 0, 0, 0};
        {
            unsigned int* po = eas + (size_t)c * 5;
            if (h == 0) {
                BU bu;
                bu.u.x = cvtpk(ea0, ea1);
                bu.u.y = cvtpk(ea2, ea3);
                bu.u.z = cvtpk(ea4, ea5);
                bu.u.w = cvtpk(ea6, ea7);
                b1 = bu.v;
                po[0] = bu.u.x; po[1] = bu.u.y; po[2] = bu.u.z; po[3] = bu.u.w;
            } else if (h == 1) {
                BU bu;
                bu.u.x = cvtpk(ea8, ea9);
                bu.u.y = 0; bu.u.z = 0; bu.u.w = 0;
                b1 = bu.v;
                po[4] = bu.u.x;
            }
        }

        const f32x4 z4 = {0.f, 0.f, 0.f, 0.f};
        f32x4 acc1[8];
#pragma unroll
        for (int f = 0; f < 8; ++f)
            acc1[f] = __builtin_amdgcn_mfma_f32_16x16x32_bf16(a1[f], b1, z4, 0, 0, 0);

        bf16x8 pb[4];
#pragma unroll
        for (int s = 0; s < 4; ++s) {
            BU bu;
            bu.u.x = cvtpk(lk(acc1[2 * s][0]), lk(acc1[2 * s][1]));
            bu.u.y = cvtpk(lk(acc1[2 * s][2]), lk(acc1[2 * s][3]));
            bu.u.z = cvtpk(lk(acc1[2 * s + 1][0]), lk(acc1[2 * s + 1][1]));
            bu.u.w = cvtpk(lk(acc1[2 * s + 1][2]), lk(acc1[2 * s + 1][3]));
            pb[s] = bu.v;
        }

        float p = 0.f;
#pragma unroll
        for (int g2 = 0; g2 < 4; ++g2) {
            const int gA = 2 * g2, gB = 2 * g2 + 1;
            const uint2 svA = sn[gA], svB = sn[gB];
            f32x4 accA, accB;
            accA[0] = __uint_as_float(svA.x << 16);
            accA[1] = __uint_as_float(svA.x & 0xffff0000u);
            accA[2] = __uint_as_float(svA.y << 16);
            accA[3] = __uint_as_float(svA.y & 0xffff0000u);
            accB[0] = __uint_as_float(svB.x << 16);
            accB[1] = __uint_as_float(svB.x & 0xffff0000u);
            accB[2] = __uint_as_float(svB.y << 16);
            accB[3] = __uint_as_float(svB.y & 0xffff0000u);
#pragma unroll
            for (int s = 0; s < 4; ++s) {
                const bf16x8 a2A = *(const bf16x8*)&w1b_s[(gA * 4 + s) * 512 + slot8];
                const bf16x8 a2B = *(const bf16x8*)&w1b_s[(gB * 4 + s) * 512 + slot8];
                accA = __builtin_amdgcn_mfma_f32_16x16x32_bf16(a2A, pb[s], accA, 0, 0, 0);
                accB = __builtin_amdgcn_mfma_f32_16x16x32_bf16(a2B, pb[s], accB, 0, 0, 0);
            }
            const float4 w2A = *(const float4*)&W2[gA * 16 + h * 4];
            const float4 w2B = *(const float4*)&W2[gB * 16 + h * 4];
            p = fmaf(fmaxf(accA[0], 0.f), w2A.x, p);
            p = fmaf(fmaxf(accA[1], 0.f), w2A.y, p);
            p = fmaf(fmaxf(accA[2], 0.f), w2A.z, p);
            p = fmaf(fmaxf(accA[3], 0.f), w2A.w, p);
            p = fmaf(fmaxf(accB[0], 0.f), w2B.x, p);
            p = fmaf(fmaxf(accB[1], 0.f), w2B.y, p);
            p = fmaf(fmaxf(accB[2], 0.f), w2B.z, p);
            p = fmaf(fmaxf(accB[3], 0.f), w2B.w, p);
        }
        p += __shfl_xor(p, 16);
        p += __shfl_xor(p, 32);
        if (lane < 16)
            e_vals[c - e15 + lane] = __expf(p + b2v);

        ptc = ptn; ptn = ptn2;
#pragma unroll
        for (int g = 0; g < 8; ++g) sn[g] = sn_n[g];
        ea0 = en0; ea1 = en1; ea2 = en2; ea3 = en3; ea4 = en4;
        ea5 = en5; ea6 = en6; ea7 = en7; ea8 = en8; ea9 = en9;
    }
}

// ---------------------------------------------------------------------------
// denom: per-node run-sum of e_vals -> inv_denom; zero boundary out-rows.
// ---------------------------------------------------------------------------
__global__ __launch_bounds__(256) void denom_kernel(
    const int* __restrict__ rowptr, const float* __restrict__ e_vals,
    float* __restrict__ inv_denom, float* __restrict__ out)
{
    const int n = blockIdx.x * 256 + threadIdx.x;
    if (n >= NN) return;
    const int rs = rowptr[n], re = rowptr[n + 1];
    float s = 0.f;
    for (int c = rs; c < re; ++c) s += e_vals[c];
    inv_denom[n] = 1.f / (s + 1e-16f);
    if (re > rs && (rs >> 6) != ((re - 1) >> 6)) {
        const float4 z = make_float4(0.f, 0.f, 0.f, 0.f);
        float4* po = (float4*)&out[(size_t)n * 128];
#pragma unroll 8
        for (int q = 0; q < 32; ++q) po[q] = z;
    }
}

// ---------------------------------------------------------------------------
// vscatter: one block per 64 sorted edges. Inline attn = e_vals*invd (and
// attn_out scatter — absorbs the former attn_kernel). v via 8 MFMA with
// C-init = bv; LDS tile reduce; complete nodes plain-store, boundary atomics.
// ---------------------------------------------------------------------------
__global__ __launch_bounds__(256) void vscatter_kernel(
    const int* __restrict__ rowptr, const int2* __restrict__ pt,
    const unsigned int* __restrict__ eas, const float* __restrict__ e_vals,
    const float* __restrict__ inv_denom,
    const unsigned short* __restrict__ wvk_g, const float* __restrict__ bv,
    float* __restrict__ out, float* __restrict__ attn_out)
{
    __shared__ __align__(16) float w_lds[64 * 132];  // 33792 B

    const int t    = threadIdx.x;
    const int lane = t & 63;
    const int wv   = t >> 6;
    const int h    = lane >> 4;
    const int e15  = lane & 15;
    const int base = blockIdx.x * 64;
    const int c    = base + wv * 16 + e15;
    const int el   = wv * 16 + e15;

    bf16x8 av[8];
#pragma unroll
    for (int g = 0; g < 8; ++g)
        av[g] = *(const bf16x8*)&wvk_g[(g * 16 + e15) * 32 + h * 8];

    const int2 pc = pt[c];
    const float at = e_vals[c] * inv_denom[pc.y];
    attn_out[pc.x] = at;

    bf16x8 be = (bf16x8){0, 0, 0, 0, 0, 0, 0, 0};
    {
        const unsigned int* pe = eas + (size_t)c * 5;
        if (h == 0) {
            BU bu;
            bu.u.x = pe[0]; bu.u.y = pe[1]; bu.u.z = pe[2]; bu.u.w = pe[3];
            be = bu.v;
        } else if (h == 1) {
            BU bu;
            bu.u.x = pe[4]; bu.u.y = 0; bu.u.z = 0; bu.u.w = 0;
            be = bu.v;
        }
    }

#pragma unroll
    for (int g = 0; g < 8; ++g) {
        const float4 bb = *(const float4*)&bv[g * 16 + h * 4];
        f32x4 cb;
        cb[0] = bb.x; cb[1] = bb.y; cb[2] = bb.z; cb[3] = bb.w;
        const f32x4 acc = __builtin_amdgcn_mfma_f32_16x16x32_bf16(av[g], be, cb, 0, 0, 0);
        float4 w;
        w.x = at * lk(acc[0]);
        w.y = at * lk(acc[1]);
        w.z = at * lk(acc[2]);
        w.w = at * lk(acc[3]);
        *(float4*)&w_lds[el * 132 + g * 16 + h * 4] = w;
    }
    __syncthreads();

    const int n_lo = (blockIdx.x == 0) ? 0 : pt[base].y;
    const int n_hi = (blockIdx.x == (int)gridDim.x - 1) ? (NN - 1) : pt[base + 64].y;

    for (int nd = n_lo + wv; nd <= n_hi; nd += 4) {
        const int rs = rowptr[nd], re = rowptr[nd + 1];
        const int lo = max(rs, base), hi = min(re, base + 64);
        float sx = 0.f, sy = 0.f;
        for (int cc = lo; cc < hi; ++cc) {
            const float2 v = *(const float2*)&w_lds[(cc - base) * 132 + lane * 2];
            sx += v.x; sy += v.y;
        }
        float* po = &out[(size_t)nd * 128 + lane * 2];
        if (rs >= base && re <= base + 64) {
            *(float2*)po = make_float2(sx, sy);
        } else {
            atomicAdd(po, sx);
            atomicAdd(po + 1, sy);
        }
    }
}

extern "C" void kernel_launch(void* const* d_in, const int* in_sizes, int n_in,
                              void* d_out, int out_size, void* d_ws, size_t ws_size,
                              hipStream_t stream)
{
    const float* x         = (const float*)d_in[0];
    const int*   eidx      = (const int*)d_in[1];
    const float* edge_attr = (const float*)d_in[2];
    const float* Wq        = (const float*)d_in[3];
    const float* Wk        = (const float*)d_in[4];
    const float* Wv        = (const float*)d_in[5];
    const float* bv        = (const float*)d_in[6];
    const float* W1        = (const float*)d_in[7];
    const float* b1        = (const float*)d_in[8];
    const float* W2        = (const float*)d_in[9];
    const float* b2        = (const float*)d_in[10];
    const int*   tgt       = eidx + NE;  // edge_index[1]

    char* ws = (char*)d_ws;
    unsigned short* w1k    = (unsigned short*)(ws + OFF_W1K);
    unsigned short* wvk    = (unsigned short*)(ws + OFF_WVK);
    unsigned short* w1bp   = (unsigned short*)(ws + OFF_W1BP);
    unsigned short* mtb    = (unsigned short*)(ws + OFF_MTB);
    int*            rowptr = (int*)(ws + OFF_RP);
    int*            cursor = (int*)(ws + OFF_CUR);
    float*          invd   = (float*)(ws + OFF_CUR);  // alias: cursor dead after fill
    int*            part   = (int*)(ws + OFF_PART);
    int*            bsum   = (int*)(ws + OFF_BSUM);
    int*            bsumx  = (int*)(ws + OFF_BSUMX);
    int*            cnt    = (int*)(ws + OFF_CNT);
    int2*           pt     = (int2*)(ws + OFF_PT);
    float*          e_vals = (float*)(ws + OFF_EVALS);
    unsigned int*   eas    = (unsigned int*)(ws + OFF_EAS);
    unsigned short* s_node = (unsigned short*)(ws + OFF_SNODE);

    float* out      = (float*)d_out;
    float* attn_out = out + (size_t)NN * 128;

    hipMemsetAsync(cnt, 0, (size_t)NN * sizeof(int), stream);

    prep_kernel<<<128, 128, 0, stream>>>(W1, Wq, Wk, Wv, w1k, wvk, w1bp, mtb);
    node_score_kernel<<<(NN + 63) / 64, 256, 0, stream>>>(x, mtb, b1, s_node);
    hist_kernel<<<(NE + 255) / 256, 256, 0, stream>>>(tgt, cnt);
    scan1_kernel<<<NB_SCAN, 256, 0, stream>>>(cnt, part, bsum);
    scan2_kernel<<<1, 512, 0, stream>>>(bsum, bsumx);
    scan3_kernel<<<NB_SCAN, 256, 0, stream>>>(part, bsumx, rowptr, cursor);
    fill_kernel<<<(NE + 255) / 256, 256, 0, stream>>>(tgt, cursor, pt);
    edge_kernel<<<1024, 256, 0, stream>>>(edge_attr, pt, w1k, w1bp, W2, b2,
                                          s_node, e_vals, eas);
    denom_kernel<<<(NN + 255) / 256, 256, 0, stream>>>(rowptr, e_vals, invd, out);
    vscatter_kernel<<<NTILES, 256, 0, stream>>>(rowptr, pt, eas, e_vals, invd,
                                                wvk, bv, out, attn_out);
}

// Round 11
// 306.001 us; speedup vs baseline: 2.2408x; 1.0480x over previous
//
#include <hip/hip_runtime.h>
#include <stdint.h>

#define NN 100000
#define NE 1000000
#define NTILES (NE / 64)
#define NB_SCAN 391  // ceil(NN/256)

typedef __attribute__((ext_vector_type(8))) short bf16x8;
typedef __attribute__((ext_vector_type(4))) float f32x4;

// ws layout (bytes)
static const size_t OFF_W1K   = 0;         // 128*32 bf16 (8 KB)
static const size_t OFF_WVK   = 8192;      // 128*32 bf16 (8 KB): Wv K-padded
static const size_t OFF_W1BP  = 16384;     // 128*128 bf16 (32 KB), slot-permuted
static const size_t OFF_MTB   = 49152;     // 128*128 bf16 (32 KB)
static const size_t OFF_RP    = 81920;     // (NN+1) int rowptr
static const size_t OFF_CUR   = 524288;    // NN int cursor; later aliased as inv_denom
static const size_t OFF_PART  = 1048576;   // NB_SCAN*256 int
static const size_t OFF_BSUM  = 1572864;   // NB_SCAN int
static const size_t OFF_BSUMX = 1576960;   // NB_SCAN int
static const size_t OFF_CNT   = 1581056;   // NN int histogram
static const size_t OFF_PT    = 2097152;   // NE int2 {edge, tgt} sorted (8 MB)
static const size_t OFF_EVALS = 10485760;  // NE f32 (sorted order, 4 MB)
static const size_t OFF_EAS   = 14485760;  // NE * 5 uint (bf16x10 packed, 20 MB)
static const size_t OFF_SNODE = 34485760;  // NN*128 bf16 (25.6 MB)

__device__ inline unsigned short f2bf(float f) {
    const unsigned int u = __float_as_uint(f);
    return (unsigned short)((u + 0x7fffu + ((u >> 16) & 1u)) >> 16);  // RNE
}

__device__ inline unsigned int cvtpk(float lo, float hi) {
    unsigned int r;
    asm("v_cvt_pk_bf16_f32 %0, %1, %2" : "=v"(r) : "v"(lo), "v"(hi));
    return r;
}

__device__ inline float lk(float v) {  // leaky_relu 0.01
    return fmaxf(v, 0.f) + 0.01f * fminf(v, 0.f);
}

union BU { bf16x8 v; uint4 u; };

// ---------------------------------------------------------------------------
// prep: w1k/wvk = bf16(Wk/Wv) K-padded to 32; w1bp = W1b slot-permuted bf16;
// mtb[i][l] = bf16((W1a@Wq)[i][l]).   (R9-exact)
// ---------------------------------------------------------------------------
__global__ __launch_bounds__(128) void prep_kernel(
    const float* __restrict__ W1, const float* __restrict__ Wq,
    const float* __restrict__ Wk, const float* __restrict__ Wv,
    unsigned short* __restrict__ w1k, unsigned short* __restrict__ wvk,
    unsigned short* __restrict__ w1bp, unsigned short* __restrict__ mtb)
{
    const int l = blockIdx.x;   // 0..127
    const int i = threadIdx.x;  // 0..127
    float acc = 0.f;
#pragma unroll 8
    for (int j = 0; j < 128; ++j)
        acc = fmaf(W1[i * 256 + j], Wq[j * 128 + l], acc);
    mtb[i * 128 + l] = f2bf(acc);
    if (i < 32) {
        w1k[l * 32 + i] = (i < 10) ? f2bf(Wk[l * 10 + i]) : (unsigned short)0;
        wvk[l * 32 + i] = (i < 10) ? f2bf(Wv[l * 10 + i]) : (unsigned short)0;
    }
    const int m = l;
    const int j = (m & ~31) + 16 * ((m >> 2) & 1) + 4 * ((m >> 3) & 3) + (m & 3);
    w1bp[i * 128 + m] = f2bf(W1[i * 256 + 128 + j]);
}

// ---------------------------------------------------------------------------
// node scores via MFMA: s_node[n][i] = bf16( x[n]@M^T + b1 ).  (R9-exact)
// ---------------------------------------------------------------------------
__global__ __launch_bounds__(256) void node_score_kernel(
    const float* __restrict__ x, const unsigned short* __restrict__ mtb_g,
    const float* __restrict__ b1, unsigned short* __restrict__ s_node)
{
    __shared__ __align__(16) unsigned short mt_s[128 * 136];
    const int t = threadIdx.x;
    for (int idx = t; idx < 2048; idx += 256) {
        const uint4 v = ((const uint4*)mtb_g)[idx];
        const int row = idx >> 4, q = idx & 15;
        *(uint4*)&mt_s[row * 136 + q * 8] = v;
    }
    __syncthreads();

    const int lane = t & 63;
    const int wave = t >> 6;
    const int h    = lane >> 4;
    const int e15  = lane & 15;
    const int node = blockIdx.x * 64 + wave * 16 + e15;
    const int nc   = min(node, NN - 1);
    const int lds_base = e15 * 136 + h * 8;

    const f32x4 z4 = {0.f, 0.f, 0.f, 0.f};
    f32x4 acc[8];
#pragma unroll
    for (int g = 0; g < 8; ++g) acc[g] = z4;

#pragma unroll
    for (int s = 0; s < 4; ++s) {
        const float4 xa = *(const float4*)&x[(size_t)nc * 128 + s * 32 + h * 8];
        const float4 xb = *(const float4*)&x[(size_t)nc * 128 + s * 32 + h * 8 + 4];
        BU bx;
        bx.u.x = cvtpk(xa.x, xa.y);
        bx.u.y = cvtpk(xa.z, xa.w);
        bx.u.z = cvtpk(xb.x, xb.y);
        bx.u.w = cvtpk(xb.z, xb.w);
#pragma unroll
        for (int g = 0; g < 8; ++g) {
            const bf16x8 a = *(const bf16x8*)&mt_s[lds_base + g * (16 * 136) + s * 32];
            acc[g] = __builtin_amdgcn_mfma_f32_16x16x32_bf16(a, bx.v, acc[g], 0, 0, 0);
        }
    }

    if (node < NN) {
#pragma unroll
        for (int g = 0; g < 8; ++g) {
            const float4 bb = *(const float4*)&b1[g * 16 + h * 4];
            uint2 o2;
            o2.x = cvtpk(acc[g][0] + bb.x, acc[g][1] + bb.y);
            o2.y = cvtpk(acc[g][2] + bb.z, acc[g][3] + bb.w);
            *(uint2*)&s_node[(size_t)node * 128 + g * 16 + h * 4] = o2;
        }
    }
}

// ---------------------------------------------------------------------------
// CSR build: histogram -> block scan -> fill {edge,tgt} pairs in sorted order
// ---------------------------------------------------------------------------
__global__ __launch_bounds__(256) void hist_kernel(
    const int* __restrict__ tgt, int* __restrict__ cnt)
{
    const int e = blockIdx.x * 256 + threadIdx.x;
    if (e < NE) atomicAdd(&cnt[tgt[e]], 1);
}

__global__ __launch_bounds__(256) void scan1_kernel(
    const int* __restrict__ cnt, int* __restrict__ part, int* __restrict__ bsum)
{
    __shared__ int s[256];
    const int t = threadIdx.x;
    const int idx = blockIdx.x * 256 + t;
    const int v = (idx < NN) ? cnt[idx] : 0;
    s[t] = v;
    __syncthreads();
    for (int off = 1; off < 256; off <<= 1) {
        const int u = (t >= off) ? s[t - off] : 0;
        __syncthreads();
        s[t] += u;
        __syncthreads();
    }
    part[idx] = s[t] - v;  // exclusive
    if (t == 255) bsum[blockIdx.x] = s[255];
}

__global__ __launch_bounds__(512) void scan2_kernel(
    const int* __restrict__ bsum, int* __restrict__ bsumx)
{
    __shared__ int s[512];
    const int t = threadIdx.x;
    const int v = (t < NB_SCAN) ? bsum[t] : 0;
    s[t] = v;
    __syncthreads();
    for (int off = 1; off < 512; off <<= 1) {
        const int u = (t >= off) ? s[t - off] : 0;
        __syncthreads();
        s[t] += u;
        __syncthreads();
    }
    if (t < NB_SCAN) bsumx[t] = s[t] - v;  // exclusive
}

__global__ __launch_bounds__(256) void scan3_kernel(
    const int* __restrict__ part, const int* __restrict__ bsumx,
    int* __restrict__ rowptr, int* __restrict__ cursor)
{
    const int idx = blockIdx.x * 256 + threadIdx.x;
    if (idx < NN) {
        const int rp = part[idx] + bsumx[idx >> 8];
        rowptr[idx] = rp;
        cursor[idx] = rp;
    }
    if (idx == 0) rowptr[NN] = NE;
}

__global__ __launch_bounds__(256) void fill_kernel(
    const int* __restrict__ tgt, int* __restrict__ cursor, int2* __restrict__ pt)
{
    const int e = blockIdx.x * 256 + threadIdx.x;
    if (e < NE) {
        const int tg = tgt[e];
        const int p  = atomicAdd(&cursor[tg], 1);
        pt[p] = make_int2(e, tg);
    }
}

// ---------------------------------------------------------------------------
// edge scores via MFMA, CSR-sorted, 2-deep software pipeline. (R9-exact 87us:
// padded-136 LDS, epilogue s_node adds, grid 768.)
// ---------------------------------------------------------------------------
__global__ __launch_bounds__(256) void edge_kernel(
    const float* __restrict__ edge_attr, const int2* __restrict__ pt,
    const unsigned short* __restrict__ w1k_g, const unsigned short* __restrict__ w1bp_g,
    const float* __restrict__ W2, const float* __restrict__ b2,
    const unsigned short* __restrict__ s_node,
    float* __restrict__ e_vals, unsigned int* __restrict__ eas)
{
    __shared__ __align__(16) unsigned short w1b_s[128 * 136];

    const int t = threadIdx.x;
    for (int idx = t; idx < 2048; idx += 256) {
        const uint4 v = ((const uint4*)w1bp_g)[idx];
        const int row = idx >> 4, q = idx & 15;
        *(uint4*)&w1b_s[row * 136 + q * 8] = v;
    }

    const int lane = t & 63;
    const int wave = t >> 6;
    const int h    = lane >> 4;
    const int e15  = lane & 15;

    bf16x8 a1[8];
#pragma unroll
    for (int f = 0; f < 8; ++f)
        a1[f] = *(const bf16x8*)&w1k_g[(f * 16 + e15) * 32 + h * 8];
    const float b2v = b2[0];

    __syncthreads();

    const int lds_base = e15 * 136 + h * 8;
    const int cstep    = gridDim.x * 64;

    int c = blockIdx.x * 64 + wave * 16 + e15;  // sorted edge index

    int2 ptc = pt[min(c, NE - 1)];
    int2 ptn = pt[min(c + cstep, NE - 1)];

    uint2 sn[8];
#pragma unroll
    for (int g = 0; g < 8; ++g)
        sn[g] = *(const uint2*)&s_node[(size_t)ptc.y * 128 + g * 16 + h * 4];

    float ea0 = 0.f, ea1 = 0.f, ea2 = 0.f, ea3 = 0.f, ea4 = 0.f;
    float ea5 = 0.f, ea6 = 0.f, ea7 = 0.f, ea8 = 0.f, ea9 = 0.f;
    {
        const float* pa = edge_attr + (size_t)ptc.x * 10;
        if (h == 0) {
            const float2 u0 = *(const float2*)(pa + 0);
            const float2 u1 = *(const float2*)(pa + 2);
            const float2 u2 = *(const float2*)(pa + 4);
            const float2 u3 = *(const float2*)(pa + 6);
            ea0 = u0.x; ea1 = u0.y; ea2 = u1.x; ea3 = u1.y;
            ea4 = u2.x; ea5 = u2.y; ea6 = u3.x; ea7 = u3.y;
        } else if (h == 1) {
            const float2 u4 = *(const float2*)(pa + 8);
            ea8 = u4.x; ea9 = u4.y;
        }
    }

    for (int tile = blockIdx.x; tile < NTILES; tile += gridDim.x, c += cstep) {
        const int2 ptn2 = pt[min(c + 2 * cstep, NE - 1)];
        uint2 sn_n[8];
#pragma unroll
        for (int g = 0; g < 8; ++g)
            sn_n[g] = *(const uint2*)&s_node[(size_t)ptn.y * 128 + g * 16 + h * 4];
        float en0 = 0.f, en1 = 0.f, en2 = 0.f, en3 = 0.f, en4 = 0.f;
        float en5 = 0.f, en6 = 0.f, en7 = 0.f, en8 = 0.f, en9 = 0.f;
        {
            const float* pa = edge_attr + (size_t)ptn.x * 10;
            if (h == 0) {
                const float2 u0 = *(const float2*)(pa + 0);
                const float2 u1 = *(const float2*)(pa + 2);
                const float2 u2 = *(const float2*)(pa + 4);
                const float2 u3 = *(const float2*)(pa + 6);
                en0 = u0.x; en1 = u0.y; en2 = u1.x; en3 = u1.y;
                en4 = u2.x; en5 = u2.y; en6 = u3.x; en7 = u3.y;
            } else if (h == 1) {
                const float2 u4 = *(const float2*)(pa + 8);
                en8 = u4.x; en9 = u4.y;
            }
        }

        bf16x8 b1 = (bf16x8){0, 0, 0, 0, 0, 0, 0, 0};
        {
            unsigned int* po = eas + (size_t)c * 5;
            if (h == 0) {
                BU bu;
                bu.u.x = cvtpk(ea0, ea1);
                bu.u.y = cvtpk(ea2, ea3);
                bu.u.z = cvtpk(ea4, ea5);
                bu.u.w = cvtpk(ea6, ea7);
                b1 = bu.v;
                po[0] = bu.u.x; po[1] = bu.u.y; po[2] = bu.u.z; po[3] = bu.u.w;
            } else if (h == 1) {
                BU bu;
                bu.u.x = cvtpk(ea8, ea9);
                bu.u.y = 0; bu.u.z = 0; bu.u.w = 0;
                b1 = bu.v;
                po[4] = bu.u.x;
            }
        }

        const f32x4 z4 = {0.f, 0.f, 0.f, 0.f};
        f32x4 acc1[8];
#pragma unroll
        for (int f = 0; f < 8; ++f)
            acc1[f] = __builtin_amdgcn_mfma_f32_16x16x32_bf16(a1[f], b1, z4, 0, 0, 0);

        bf16x8 pb[4];
#pragma unroll
        for (int s = 0; s < 4; ++s) {
            BU bu;
            bu.u.x = cvtpk(lk(acc1[2 * s][0]), lk(acc1[2 * s][1]));
            bu.u.y = cvtpk(lk(acc1[2 * s][2]), lk(acc1[2 * s][3]));
            bu.u.z = cvtpk(lk(acc1[2 * s + 1][0]), lk(acc1[2 * s + 1][1]));
            bu.u.w = cvtpk(lk(acc1[2 * s + 1][2]), lk(acc1[2 * s + 1][3]));
            pb[s] = bu.v;
        }

        float p = 0.f;
#pragma unroll
        for (int g2 = 0; g2 < 4; ++g2) {
            const int gA = 2 * g2, gB = 2 * g2 + 1;
            f32x4 accA = z4, accB = z4;
#pragma unroll
            for (int s = 0; s < 4; ++s) {
                const bf16x8 a2A = *(const bf16x8*)&w1b_s[lds_base + gA * (16 * 136) + s * 32];
                const bf16x8 a2B = *(const bf16x8*)&w1b_s[lds_base + gB * (16 * 136) + s * 32];
                accA = __builtin_amdgcn_mfma_f32_16x16x32_bf16(a2A, pb[s], accA, 0, 0, 0);
                accB = __builtin_amdgcn_mfma_f32_16x16x32_bf16(a2B, pb[s], accB, 0, 0, 0);
            }
            const float4 w2A = *(const float4*)&W2[gA * 16 + h * 4];
            const float4 w2B = *(const float4*)&W2[gB * 16 + h * 4];
            const uint2 svA = sn[gA], svB = sn[gB];
            p = fmaf(fmaxf(accA[0] + __uint_as_float(svA.x << 16), 0.f), w2A.x, p);
            p = fmaf(fmaxf(accA[1] + __uint_as_float(svA.x & 0xffff0000u), 0.f), w2A.y, p);
            p = fmaf(fmaxf(accA[2] + __uint_as_float(svA.y << 16), 0.f), w2A.z, p);
            p = fmaf(fmaxf(accA[3] + __uint_as_float(svA.y & 0xffff0000u), 0.f), w2A.w, p);
            p = fmaf(fmaxf(accB[0] + __uint_as_float(svB.x << 16), 0.f), w2B.x, p);
            p = fmaf(fmaxf(accB[1] + __uint_as_float(svB.x & 0xffff0000u), 0.f), w2B.y, p);
            p = fmaf(fmaxf(accB[2] + __uint_as_float(svB.y << 16), 0.f), w2B.z, p);
            p = fmaf(fmaxf(accB[3] + __uint_as_float(svB.y & 0xffff0000u), 0.f), w2B.w, p);
        }
        p += __shfl_xor(p, 16);
        p += __shfl_xor(p, 32);
        if (lane < 16)
            e_vals[c - e15 + lane] = __expf(p + b2v);

        ptc = ptn; ptn = ptn2;
#pragma unroll
        for (int g = 0; g < 8; ++g) sn[g] = sn_n[g];
        ea0 = en0; ea1 = en1; ea2 = en2; ea3 = en3; ea4 = en4;
        ea5 = en5; ea6 = en6; ea7 = en7; ea8 = en8; ea9 = en9;
    }
}

// ---------------------------------------------------------------------------
// denom: per-node run-sum of e_vals -> inv_denom; zero boundary out-rows.
// ---------------------------------------------------------------------------
__global__ __launch_bounds__(256) void denom_kernel(
    const int* __restrict__ rowptr, const float* __restrict__ e_vals,
    float* __restrict__ inv_denom, float* __restrict__ out)
{
    const int n = blockIdx.x * 256 + threadIdx.x;
    if (n >= NN) return;
    const int rs = rowptr[n], re = rowptr[n + 1];
    float s = 0.f;
    for (int c = rs; c < re; ++c) s += e_vals[c];
    inv_denom[n] = 1.f / (s + 1e-16f);
    if (re > rs && (rs >> 6) != ((re - 1) >> 6)) {
        const float4 z = make_float4(0.f, 0.f, 0.f, 0.f);
        float4* po = (float4*)&out[(size_t)n * 128];
#pragma unroll 8
        for (int q = 0; q < 32; ++q) po[q] = z;
    }
}

// ---------------------------------------------------------------------------
// vscatter: PERSISTENT grid (weights hoisted once per block). Per 64-edge
// tile: inline attn = e_vals*invd (+ attn_out scatter, h==0 only); v via
// 8 MFMA (C-init = bv); LDS tile; rowptr-guided segment reduce; complete
// nodes plain-store, boundary nodes atomicAdd onto pre-zeroed rows.
// ---------------------------------------------------------------------------
__global__ __launch_bounds__(256) void vscatter_kernel(
    const int* __restrict__ rowptr, const int2* __restrict__ pt,
    const unsigned int* __restrict__ eas, const float* __restrict__ e_vals,
    const float* __restrict__ inv_denom,
    const unsigned short* __restrict__ wvk_g, const float* __restrict__ bv,
    float* __restrict__ out, float* __restrict__ attn_out)
{
    __shared__ __align__(16) float w_lds[64 * 132];  // 33792 B

    const int t    = threadIdx.x;
    const int lane = t & 63;
    const int wv   = t >> 6;
    const int h    = lane >> 4;
    const int e15  = lane & 15;
    const int el   = wv * 16 + e15;

    // hoisted: Wv A-frags + bias (live across all tiles)
    bf16x8 av[8];
    float4 bb[8];
#pragma unroll
    for (int g = 0; g < 8; ++g) {
        av[g] = *(const bf16x8*)&wvk_g[(g * 16 + e15) * 32 + h * 8];
        bb[g] = *(const float4*)&bv[g * 16 + h * 4];
    }

    for (int tile = blockIdx.x; tile < NTILES; tile += gridDim.x) {
        const int base = tile * 64;
        const int c    = base + el;

        const int2 pc = pt[c];
        const float at = e_vals[c] * inv_denom[pc.y];
        if (h == 0) attn_out[pc.x] = at;

        bf16x8 be = (bf16x8){0, 0, 0, 0, 0, 0, 0, 0};
        {
            const unsigned int* pe = eas + (size_t)c * 5;
            if (h == 0) {
                BU bu;
                bu.u.x = pe[0]; bu.u.y = pe[1]; bu.u.z = pe[2]; bu.u.w = pe[3];
                be = bu.v;
            } else if (h == 1) {
                BU bu;
                bu.u.x = pe[4]; bu.u.y = 0; bu.u.z = 0; bu.u.w = 0;
                be = bu.v;
            }
        }

        __syncthreads();  // protect w_lds from previous tile's readers
#pragma unroll
        for (int g = 0; g < 8; ++g) {
            f32x4 cb;
            cb[0] = bb[g].x; cb[1] = bb[g].y; cb[2] = bb[g].z; cb[3] = bb[g].w;
            const f32x4 acc = __builtin_amdgcn_mfma_f32_16x16x32_bf16(av[g], be, cb, 0, 0, 0);
            float4 w;
            w.x = at * lk(acc[0]);
            w.y = at * lk(acc[1]);
            w.z = at * lk(acc[2]);
            w.w = at * lk(acc[3]);
            *(float4*)&w_lds[el * 132 + g * 16 + h * 4] = w;
        }
        __syncthreads();

        const int n_lo = (tile == 0) ? 0 : pt[base].y;
        const int n_hi = (tile == NTILES - 1) ? (NN - 1) : pt[base + 64].y;

        for (int nd = n_lo + wv; nd <= n_hi; nd += 4) {
            const int rs = rowptr[nd], re = rowptr[nd + 1];
            const int lo = max(rs, base), hi = min(re, base + 64);
            float sx = 0.f, sy = 0.f;
            for (int cc = lo; cc < hi; ++cc) {
                const float2 v = *(const float2*)&w_lds[(cc - base) * 132 + lane * 2];
                sx += v.x; sy += v.y;
            }
            float* po = &out[(size_t)nd * 128 + lane * 2];
            if (rs >= base && re <= base + 64) {
                *(float2*)po = make_float2(sx, sy);
            } else {
                atomicAdd(po, sx);
                atomicAdd(po + 1, sy);
            }
        }
    }
}

extern "C" void kernel_launch(void* const* d_in, const int* in_sizes, int n_in,
                              void* d_out, int out_size, void* d_ws, size_t ws_size,
                              hipStream_t stream)
{
    const float* x         = (const float*)d_in[0];
    const int*   eidx      = (const int*)d_in[1];
    const float* edge_attr = (const float*)d_in[2];
    const float* Wq        = (const float*)d_in[3];
    const float* Wk        = (const float*)d_in[4];
    const float* Wv        = (const float*)d_in[5];
    const float* bv        = (const float*)d_in[6];
    const float* W1        = (const float*)d_in[7];
    const float* b1        = (const float*)d_in[8];
    const float* W2        = (const float*)d_in[9];
    const float* b2        = (const float*)d_in[10];
    const int*   tgt       = eidx + NE;  // edge_index[1]

    char* ws = (char*)d_ws;
    unsigned short* w1k    = (unsigned short*)(ws + OFF_W1K);
    unsigned short* wvk    = (unsigned short*)(ws + OFF_WVK);
    unsigned short* w1bp   = (unsigned short*)(ws + OFF_W1BP);
    unsigned short* mtb    = (unsigned short*)(ws + OFF_MTB);
    int*            rowptr = (int*)(ws + OFF_RP);
    int*            cursor = (int*)(ws + OFF_CUR);
    float*          invd   = (float*)(ws + OFF_CUR);  // alias: cursor dead after fill
    int*            part   = (int*)(ws + OFF_PART);
    int*            bsum   = (int*)(ws + OFF_BSUM);
    int*            bsumx  = (int*)(ws + OFF_BSUMX);
    int*            cnt    = (int*)(ws + OFF_CNT);
    int2*           pt     = (int2*)(ws + OFF_PT);
    float*          e_vals = (float*)(ws + OFF_EVALS);
    unsigned int*   eas    = (unsigned int*)(ws + OFF_EAS);
    unsigned short* s_node = (unsigned short*)(ws + OFF_SNODE);

    float* out      = (float*)d_out;
    float* attn_out = out + (size_t)NN * 128;

    hipMemsetAsync(cnt, 0, (size_t)NN * sizeof(int), stream);

    prep_kernel<<<128, 128, 0, stream>>>(W1, Wq, Wk, Wv, w1k, wvk, w1bp, mtb);
    node_score_kernel<<<(NN + 63) / 64, 256, 0, stream>>>(x, mtb, b1, s_node);
    hist_kernel<<<(NE + 255) / 256, 256, 0, stream>>>(tgt, cnt);
    scan1_kernel<<<NB_SCAN, 256, 0, stream>>>(cnt, part, bsum);
    scan2_kernel<<<1, 512, 0, stream>>>(bsum, bsumx);
    scan3_kernel<<<NB_SCAN, 256, 0, stream>>>(part, bsumx, rowptr, cursor);
    fill_kernel<<<(NE + 255) / 256, 256, 0, stream>>>(tgt, cursor, pt);
    edge_kernel<<<768, 256, 0, stream>>>(edge_attr, pt, w1k, w1bp, W2, b2,
                                         s_node, e_vals, eas);
    denom_kernel<<<(NN + 255) / 256, 256, 0, stream>>>(rowptr, e_vals, invd, out);
    vscatter_kernel<<<1024, 256, 0, stream>>>(rowptr, pt, eas, e_vals, invd,
                                              wvk, bv, out, attn_out);
}